// Round 5
// baseline (202.572 us; speedup 1.0000x reference)
//
#include <hip/hip_runtime.h>
#include <hip/hip_bf16.h>
#include <math.h>
#include <stdint.h>
#include <string.h>

#define TSEQ 2048
#define DMODEL 1024
#define NH 16
#define HD 64
#define BROWS 4096   // b*t
#define BH 32        // b*h

typedef __attribute__((ext_vector_type(8))) short short8;
typedef __attribute__((ext_vector_type(4))) float floatx4;
typedef __attribute__((ext_vector_type(16))) float floatx16;

#define MFMA16 __builtin_amdgcn_mfma_f32_16x16x32_bf16
#define MFMA32 __builtin_amdgcn_mfma_f32_32x32x16_bf16
// 3-bit chunk-XOR swizzle on 64-short (128 B) rows
#define SWZ8(r, q) ((((q) ^ ((r) & 7)) * 8))

#define QSCALE 0.18033688011112042f   // 0.125 * log2(e); p = exp2(s) = exp(s/log2e)

__device__ __forceinline__ unsigned short bf16_rne(float f) {
    uint32_t u = __float_as_uint(f);
    u += 0x7FFFu + ((u >> 16) & 1u);
    return (unsigned short)(u >> 16);
}

__device__ __forceinline__ uint32_t pack_bf16x2(float a, float b) {
    __hip_bfloat162 h = __float22bfloat162_rn(float2{a, b});
    uint32_t r;
    memcpy(&r, &h, 4);
    return r;
}

__device__ __forceinline__ void split_bf16(float f, short& hi, short& lo) {
    uint32_t u = __float_as_uint(f);
    hi = (short)(u >> 16);
    float hif = __uint_as_float(u & 0xFFFF0000u);
    lo = (short)bf16_rne(f - hif);
}

__device__ __forceinline__ void async16(const void* g, void* l) {
    __builtin_amdgcn_global_load_lds(
        (__attribute__((address_space(1))) const uint32_t*)g,
        (__attribute__((address_space(3))) uint32_t*)l, 16, 0, 0);
}

// ---------------------------------------------------------------------------
// Fused pack (unchanged)
// ---------------------------------------------------------------------------
struct PackArgs {
    const float4* x;
    ushort4* xb;
    const float4* w[3];   // Wq, Wk, Wv
    ushort4* wb[3];
    const float4* wo;
    ushort4* woh;
    ushort4* wol;
};
__global__ __launch_bounds__(256) void pack_all(PackArgs a) {
    const int y = blockIdx.y;
    const int base = blockIdx.x * 256 + threadIdx.x;
    if (y == 0) {
#pragma unroll
        for (int it = 0; it < 4; ++it) {
            int i = base + it * 262144;
            float4 f = a.x[i];
            a.xb[i] = make_ushort4(bf16_rne(f.x), bf16_rne(f.y),
                                   bf16_rne(f.z), bf16_rne(f.w));
        }
    } else if (y <= 3) {
        int w = y - 1;
        float4 f = a.w[w][base];
        a.wb[w][base] = make_ushort4(bf16_rne(f.x), bf16_rne(f.y),
                                     bf16_rne(f.z), bf16_rne(f.w));
    } else {
        float4 f = a.wo[base];
        short h0, l0, h1, l1, h2, l2, h3, l3;
        split_bf16(f.x, h0, l0); split_bf16(f.y, h1, l1);
        split_bf16(f.z, h2, l2); split_bf16(f.w, h3, l3);
        a.woh[base] = make_ushort4(h0, h1, h2, h3);
        a.wol[base] = make_ushort4(l0, l1, l2, l3);
    }
}

// ---------------------------------------------------------------------------
// Fused QKV single-bf16 GEMM. 128x128, BK=64, 768 blocks. (unchanged from R3)
// V: [bh][hd][t]; within-64-window key positions permuted by sigma =
//    swap(bit2,bit3) so attn's 32x32 PV B-operand is regs 8c..8c+7 of the QK
//    accumulator directly; then chunk-XOR by hd&7.
// ---------------------------------------------------------------------------
__global__ __launch_bounds__(256) void gemm_qkv(
    const short* __restrict__ Xb,
    const short* __restrict__ Bq, const short* __restrict__ Bk,
    const short* __restrict__ Bv,
    short* __restrict__ Qo, short* __restrict__ Ko, short* __restrict__ Vo) {
    __shared__ short sA[128 * 64];
    __shared__ short sB[128 * 64];
    const int K = DMODEL;

    const int tid = threadIdx.x;
    const int lane = tid & 63, wave = tid >> 6;
    const int quad = lane >> 4, col = lane & 15;
    const int m0 = blockIdx.y * 128, n0 = blockIdx.x * 128;
    const int which = n0 >> 10;
    const int nn0 = n0 & 1023;
    const int wm = wave >> 1, wn = wave & 1;

    const short* B = (which == 0) ? Bq : (which == 1) ? Bk : Bv;
    const short* Asrc = Xb + (size_t)m0 * K;
    const short* Bsrc = B + (size_t)nn0 * K;

    const int srow = lane >> 3;
    const int soff = (((lane & 7) ^ srow) * 8);

    floatx4 acc[4][4] = {};

    for (int k0 = 0; k0 < K; k0 += 64) {
        __syncthreads();
#pragma unroll
        for (int j = 0; j < 8; ++j) {
            int idx = wave * 8 + j;
            int sub = idx & 15;
            const short* s = (idx < 16) ? Asrc : Bsrc;
            short* d = (idx < 16) ? sA : sB;
            async16(s + (size_t)(sub * 8 + srow) * K + k0 + soff, d + sub * 512);
        }
        __syncthreads();

#pragma unroll
        for (int s2 = 0; s2 < 2; ++s2) {
            short8 a_b[4], b_b[4];
#pragma unroll
            for (int mi = 0; mi < 4; ++mi) {
                int r = wm * 64 + mi * 16 + col;
                a_b[mi] = *(const short8*)&sA[r * 64 + SWZ8(r, s2 * 4 + quad)];
            }
#pragma unroll
            for (int ni = 0; ni < 4; ++ni) {
                int r = wn * 64 + ni * 16 + col;
                b_b[ni] = *(const short8*)&sB[r * 64 + SWZ8(r, s2 * 4 + quad)];
            }
            if (which == 2) {
#pragma unroll
                for (int mi = 0; mi < 4; ++mi)
#pragma unroll
                    for (int ni = 0; ni < 4; ++ni)
                        acc[mi][ni] = MFMA16(a_b[mi], b_b[ni], acc[mi][ni], 0, 0, 0);
            } else {
#pragma unroll
                for (int mi = 0; mi < 4; ++mi)
#pragma unroll
                    for (int ni = 0; ni < 4; ++ni)
                        acc[mi][ni] = MFMA16(b_b[ni], a_b[mi], acc[mi][ni], 0, 0, 0);
            }
        }
    }

    const int mb = m0 + wm * 64;
    const int nlb = nn0 + wn * 64;
    if (which == 2) {
        // V^T [bh][hd][t], sigma = swap(bit2,bit3) of local key + chunk-XOR
#pragma unroll
        for (int ni = 0; ni < 4; ++ni) {
            int n = nlb + ni * 16 + col;
            int h = n >> 6, hd = n & 63;
#pragma unroll
            for (int mi = 0; mi < 4; ++mi) {
                int m4 = mb + mi * 16 + quad * 4;
                int b = m4 >> 11, t0 = m4 & 2047;
                // sigma: swap bits 2 and 3 of the key index (involution)
                int sw = (t0 & 0x33) | ((t0 & 4) << 1) | ((t0 & 8) >> 1);
                int tsw = (t0 & ~63) | ((((sw >> 3) ^ (hd & 7)) << 3) | (sw & 7));
                size_t row = ((size_t)(b * NH + h) * HD + hd) * TSEQ;
                *(ushort4*)&Vo[row + tsw] =
                    make_ushort4(bf16_rne(acc[mi][ni][0]), bf16_rne(acc[mi][ni][1]),
                                 bf16_rne(acc[mi][ni][2]), bf16_rne(acc[mi][ni][3]));
            }
        }
    } else {
        short* O = (which == 0) ? Qo : Ko;
        const float sc = (which == 0) ? QSCALE : 1.0f;
#pragma unroll
        for (int mi = 0; mi < 4; ++mi) {
            int m = mb + mi * 16 + col;
            int b = m >> 11, t = m & 2047;
#pragma unroll
            for (int ni = 0; ni < 4; ++ni) {
                int n = nlb + ni * 16 + quad * 4;
                int h = n >> 6, hd = n & 63;
                int hds = (which == 1) ? ((((hd >> 3) ^ (t & 7)) << 3) | (hd & 7)) : hd;
                size_t idx = ((size_t)(b * NH + h) * TSEQ + t) * HD + hds;
                *(ushort4*)&O[idx] =
                    make_ushort4(bf16_rne(acc[mi][ni][0] * sc), bf16_rne(acc[mi][ni][1] * sc),
                                 bf16_rne(acc[mi][ni][2] * sc), bf16_rne(acc[mi][ni][3] * sc));
            }
        }
    }
}

// ---------------------------------------------------------------------------
// Flash attention, 32x32 MFMA, key-split TLP form (R5).
// R4 showed no pipe >43% with 2 waves/SIMD -> latency-bound. Now 512 thr =
// 8 waves = 4 q-groups x 2 KEY-STREAMS (each stream owns 1024 keys, 16 chunks
// of 64). Partial O/l merge once at the end via LDS (no running max exists,
// partials just add). 64 KB LDS -> 2 blocks/CU -> 16 waves/CU = 4 waves/SIMD
// (2x R4). Per-chunk math identical to R4's verified 64-key subtile.
// ---------------------------------------------------------------------------
#define ATTN_CHUNK(DB)                                                          \
    {                                                                           \
        floatx16 s2[2] = {};                                                    \
        __builtin_amdgcn_s_setprio(1);                                          \
        _Pragma("unroll")                                                       \
        for (int mm = 0; mm < 2; ++mm)                                          \
            _Pragma("unroll")                                                   \
            for (int ks = 0; ks < 4; ++ks) {                                    \
                short8 kf = *(const short8*)(kBp[ks] + (DB) * 4096 + mm * 2048);\
                s2[mm] = MFMA32(kf, qf[ks], s2[mm], 0, 0, 0);                   \
            }                                                                   \
        __builtin_amdgcn_s_setprio(0);                                          \
        _Pragma("unroll")                                                       \
        for (int mm = 0; mm < 2; ++mm) {                                        \
            float p[16];                                                        \
            _Pragma("unroll")                                                   \
            for (int r = 0; r < 16; ++r) {                                      \
                p[r] = __builtin_amdgcn_exp2f(s2[mm][r]);                       \
                lv[r & 3] += p[r];                                              \
            }                                                                   \
            _Pragma("unroll")                                                   \
            for (int c = 0; c < 2; ++c) {                                       \
                union { short8 v; uint32_t w[4]; } pf;                          \
                pf.w[0] = pack_bf16x2(p[8 * c + 0], p[8 * c + 1]);              \
                pf.w[1] = pack_bf16x2(p[8 * c + 2], p[8 * c + 3]);              \
                pf.w[2] = pack_bf16x2(p[8 * c + 4], p[8 * c + 5]);              \
                pf.w[3] = pack_bf16x2(p[8 * c + 6], p[8 * c + 7]);              \
                const int tt = mm * 2 + c;                                      \
                __builtin_amdgcn_s_setprio(1);                                  \
                _Pragma("unroll")                                               \
                for (int mi = 0; mi < 2; ++mi) {                                \
                    short8 vf = *(const short8*)(vBp[tt] + (DB) * 4096 + mi * 2048); \
                    O2[mi] = MFMA32(vf, pf.v, O2[mi], 0, 0, 0);                 \
                }                                                               \
                __builtin_amdgcn_s_setprio(0);                                  \
            }                                                                   \
        }                                                                       \
    }

#define STAGE(LB)                                                               \
    {                                                                           \
        async16(gb + 0 * gj, (LB) + 0 * 512);                                   \
        async16(gb + 1 * gj, (LB) + 1 * 512);                                   \
        async16(gb + 2 * gj, (LB) + 2 * 512);                                   \
        async16(gb + 3 * gj, (LB) + 3 * 512);                                   \
        gb += cstep;                                                            \
    }

__global__ __launch_bounds__(512, 4) void attn_bf16(
    const short* __restrict__ Qb, const short* __restrict__ Kb,
    const short* __restrict__ Vb, short* __restrict__ Cb) {
    __shared__ short sK[2][2][4096];   // [stream][dbuf][64key x 64hd]
    __shared__ short sV[2][2][4096];   // [stream][dbuf][64hd x 64pos]

    const int tid = threadIdx.x;
    const int lane = tid & 63, wave = tid >> 6;
    const int q5 = lane & 31, hh = lane >> 5, l7 = lane & 7;
    const int qg = wave & 3;           // q-group: 32 rows
    const int st = wave >> 2;          // key-stream: 1024 keys
    const int qt = blockIdx.x, bh = blockIdx.y;
    const size_t bhoff = (size_t)bh * TSEQ * HD;

    // Q as B-operand frags: B[n=q=q5][k = hh*8+j + 16*ks]
    const size_t qrow = (size_t)(qt * 128 + qg * 32 + q5) * HD;
    short8 qf[4];
#pragma unroll
    for (int ks = 0; ks < 4; ++ks)
        qf[ks] = *(const short8*)&Qb[bhoff + qrow + ks * 16 + hh * 8];

    // staging: within each stream, role qg: 0/1 = K halves, 2/3 = V halves.
    // Each wave issues exactly 4 async16 (4 KB) per 64-key chunk.
    const int srow = lane >> 3, schunk = (lane & 7) * 8;
    const int isV = qg >> 1, half = qg & 1;
    const short* gb;
    size_t gj, cstep;
    if (!isV) {
        gb = Kb + bhoff + (size_t)(st * 1024 + half * 32 + srow) * HD + schunk;
        gj = (size_t)8 * HD;
        cstep = (size_t)64 * HD;
    } else {
        gb = Vb + bhoff + (size_t)(half * 32 + srow) * TSEQ + st * 1024 + schunk;
        gj = (size_t)8 * TSEQ;
        cstep = 64;
    }
    short (*dst)[4096] = isV ? sV[st] : sK[st];
    short* lb0 = dst[0] + half * 2048;
    short* lb1 = dst[1] + half * 2048;

    // fragment-read bases: all ds_reads = base + compile-time imm
    const short *kBp[4], *vBp[4];
#pragma unroll
    for (int w = 0; w < 4; ++w) {
        kBp[w] = &sK[st][0][q5 * 64 + (((2 * w + hh) ^ l7) * 8)];
        vBp[w] = &sV[st][0][q5 * 64 + (((2 * w + hh) ^ l7) * 8)];
    }

    floatx4 lv = {};        // l partial (this lane's p-values)
    floatx16 O2[2] = {};    // O^T partial: hd = 32*mi + (r&3)+8*(r>>2)+4*hh, q = q5

    STAGE(lb0);             // chunk 0 -> db0

    for (int c2 = 0; c2 < 8; ++c2) {
        STAGE(lb1);
        asm volatile("s_waitcnt vmcnt(4)" ::: "memory");
        __builtin_amdgcn_s_barrier();
        ATTN_CHUNK(0);
        __builtin_amdgcn_s_barrier();

        if (c2 < 7) {
            STAGE(lb0);
            asm volatile("s_waitcnt vmcnt(4)" ::: "memory");
        } else {
            asm volatile("s_waitcnt vmcnt(0)" ::: "memory");
        }
        __builtin_amdgcn_s_barrier();
        ATTN_CHUNK(1);
        __builtin_amdgcn_s_barrier();
    }

    // ---- merge the two key-streams (partial sums just add) ----
    float lp = (lv[0] + lv[1]) + (lv[2] + lv[3]);
    float* xch = (float*)&sK[0][0][0];   // 8192 floats = 32 KB
    float* xl  = (float*)&sV[0][0][0];
    __syncthreads();
    if (st == 1) {
#pragma unroll
        for (int j = 0; j < 8; ++j) {
            float4 v = make_float4(O2[j >> 2][(j & 3) * 4 + 0],
                                   O2[j >> 2][(j & 3) * 4 + 1],
                                   O2[j >> 2][(j & 3) * 4 + 2],
                                   O2[j >> 2][(j & 3) * 4 + 3]);
            *(float4*)&xch[qg * 2048 + lane * 32 + ((j ^ l7) * 4)] = v;
        }
        xl[qg * 64 + lane] = lp;
    }
    __syncthreads();
    if (st == 0) {
        lp += xl[qg * 64 + lane];
        lp += __shfl_xor(lp, 32);
        const float inv = 1.0f / lp;

        const int b = bh >> 4, h = bh & 15;
        const int trow = qt * 128 + qg * 32 + q5;
        const size_t obase = (size_t)(b * TSEQ + trow) * DMODEL + h * 64;
#pragma unroll
        for (int j = 0; j < 8; j += 2) {
            float4 oa = *(const float4*)&xch[qg * 2048 + lane * 32 + ((j ^ l7) * 4)];
            float4 ob = *(const float4*)&xch[qg * 2048 + lane * 32 + (((j + 1) ^ l7) * 4)];
            uint2 pk;
            pk.x = pack_bf16x2((O2[j >> 2][(j & 3) * 4 + 0] + oa.x) * inv,
                               (O2[j >> 2][(j & 3) * 4 + 1] + oa.y) * inv);
            pk.y = pack_bf16x2((O2[j >> 2][(j & 3) * 4 + 2] + oa.z) * inv,
                               (O2[j >> 2][(j & 3) * 4 + 3] + oa.w) * inv);
            uint2 pk2;
            pk2.x = pack_bf16x2((O2[(j + 1) >> 2][((j + 1) & 3) * 4 + 0] + ob.x) * inv,
                                (O2[(j + 1) >> 2][((j + 1) & 3) * 4 + 1] + ob.y) * inv);
            pk2.y = pack_bf16x2((O2[(j + 1) >> 2][((j + 1) & 3) * 4 + 2] + ob.z) * inv,
                                (O2[(j + 1) >> 2][((j + 1) & 3) * 4 + 3] + ob.w) * inv);
            // j = mi*4+g: col = mi*32 + g*8 + hh*4
            *(uint2*)&Cb[obase + (j >> 2) * 32 + (j & 3) * 8 + hh * 4] = pk;
            *(uint2*)&Cb[obase + ((j + 1) >> 2) * 32 + ((j + 1) & 3) * 8 + hh * 4] = pk2;
        }
    }
}

// ---------------------------------------------------------------------------
// Out-proj 2-term, operand-flipped (unchanged). 128x64, BK=64.
// ---------------------------------------------------------------------------
__global__ __launch_bounds__(256) void gemm_out(
    const short* __restrict__ Ab,
    const short* __restrict__ Bh, const short* __restrict__ Bl,
    const float* __restrict__ bias, float* __restrict__ Of) {
    __shared__ short sA[128 * 64];
    __shared__ short sBh[64 * 64];
    __shared__ short sBl[64 * 64];
    const int K = DMODEL, N = DMODEL;

    const int tid = threadIdx.x;
    const int lane = tid & 63, wave = tid >> 6;
    const int quad = lane >> 4, col = lane & 15;
    const int m0 = blockIdx.y * 128, n0 = blockIdx.x * 64;
    const int wm = wave >> 1, wn = wave & 1;

    const short* Asrc = Ab + (size_t)m0 * K;
    const short* Bhsrc = Bh + (size_t)n0 * K;
    const short* Blsrc = Bl + (size_t)n0 * K;
    const int srow = lane >> 3;
    const int soff = (((lane & 7) ^ srow) * 8);

    floatx4 acc[4][2] = {};

    for (int k0 = 0; k0 < K; k0 += 64) {
        __syncthreads();
#pragma unroll
        for (int j = 0; j < 8; ++j) {
            int idx = wave * 8 + j;
            int buf = (idx < 16) ? 0 : (idx < 24) ? 1 : 2;
            int sub = (buf == 0) ? idx : (buf == 1) ? idx - 16 : idx - 24;
            const short* s = (buf == 0) ? Asrc : (buf == 1) ? Bhsrc : Blsrc;
            short* d = (buf == 0) ? sA : (buf == 1) ? sBh : sBl;
            async16(s + (size_t)(sub * 8 + srow) * K + k0 + soff, d + sub * 512);
        }
        __syncthreads();

#pragma unroll
        for (int s2 = 0; s2 < 2; ++s2) {
            short8 a_b[4], b_h[2], b_l[2];
#pragma unroll
            for (int mi = 0; mi < 4; ++mi) {
                int r = wm * 64 + mi * 16 + col;
                a_b[mi] = *(const short8*)&sA[r * 64 + SWZ8(r, s2 * 4 + quad)];
            }
#pragma unroll
            for (int ni = 0; ni < 2; ++ni) {
                int r = wn * 32 + ni * 16 + col;
                b_h[ni] = *(const short8*)&sBh[r * 64 + SWZ8(r, s2 * 4 + quad)];
                b_l[ni] = *(const short8*)&sBl[r * 64 + SWZ8(r, s2 * 4 + quad)];
            }
#pragma unroll
            for (int mi = 0; mi < 4; ++mi)
#pragma unroll
                for (int ni = 0; ni < 2; ++ni) {
                    acc[mi][ni] = MFMA16(b_h[ni], a_b[mi], acc[mi][ni], 0, 0, 0);
                    acc[mi][ni] = MFMA16(b_l[ni], a_b[mi], acc[mi][ni], 0, 0, 0);
                }
        }
    }

    const int mb = m0 + wm * 64, nb = n0 + wn * 32;
#pragma unroll
    for (int mi = 0; mi < 4; ++mi) {
        int m = mb + mi * 16 + col;
#pragma unroll
        for (int ni = 0; ni < 2; ++ni) {
            int n = nb + ni * 16 + quad * 4;
            float4 bv = *(const float4*)&bias[n];
            float4 o = make_float4(acc[mi][ni][0] + bv.x, acc[mi][ni][1] + bv.y,
                                   acc[mi][ni][2] + bv.z, acc[mi][ni][3] + bv.w);
            *(float4*)&Of[(size_t)m * N + n] = o;
        }
    }
}

// ---------------------------------------------------------------------------
extern "C" void kernel_launch(void* const* d_in, const int* in_sizes, int n_in,
                              void* d_out, int out_size, void* d_ws, size_t ws_size,
                              hipStream_t stream) {
    const float* x  = (const float*)d_in[0];
    const float* Wq = (const float*)d_in[1];
    const float* Wk = (const float*)d_in[2];
    const float* Wv = (const float*)d_in[3];
    const float* Wo = (const float*)d_in[4];
    const float* bo = (const float*)d_in[5];
    float* out = (float*)d_out;

    const size_t NX = (size_t)BROWS * DMODEL;   // 4M
    const size_t NW = (size_t)DMODEL * DMODEL;  // 1M
    short* p = (short*)d_ws;
    short *xb = p;
    short *wqb = xb + NX;
    short *wkb = wqb + NW;
    short *wvb = wkb + NW;
    short *woh = wvb + NW; short *wol = woh + NW;
    short *qb = wol + NW;
    short *kb = qb + NX;
    short *vb = kb + NX;
    short *cb = vb + NX;

    PackArgs pa;
    pa.x = (const float4*)x; pa.xb = (ushort4*)xb;
    pa.w[0] = (const float4*)Wq; pa.wb[0] = (ushort4*)wqb;
    pa.w[1] = (const float4*)Wk; pa.wb[1] = (ushort4*)wkb;
    pa.w[2] = (const float4*)Wv; pa.wb[2] = (ushort4*)wvb;
    pa.wo = (const float4*)Wo; pa.woh = (ushort4*)woh; pa.wol = (ushort4*)wol;
    pack_all<<<dim3(1024, 5), dim3(256), 0, stream>>>(pa);

    gemm_qkv<<<dim3(3 * DMODEL / 128, BROWS / 128), dim3(256), 0, stream>>>(
        xb, wqb, wkb, wvb, qb, kb, vb);

    attn_bf16<<<dim3(TSEQ / 128, BH), dim3(512), 0, stream>>>(qb, kb, vb, cb);

    gemm_out<<<dim3(DMODEL / 64, BROWS / 128), dim3(256), 0, stream>>>(cb, woh, wol, bo, out);
}

// Round 6
// 190.760 us; speedup vs baseline: 1.0619x; 1.0619x over previous
//
#include <hip/hip_runtime.h>
#include <hip/hip_bf16.h>
#include <math.h>
#include <stdint.h>
#include <string.h>

#define TSEQ 2048
#define DMODEL 1024
#define NH 16
#define HD 64
#define BROWS 4096   // b*t
#define BH 32        // b*h

typedef __attribute__((ext_vector_type(8))) short short8;
typedef __attribute__((ext_vector_type(4))) float floatx4;

#define MFMA16 __builtin_amdgcn_mfma_f32_16x16x32_bf16
// 3-bit chunk-XOR swizzle on 64-short (128 B) rows
#define SWZ8(r, q) ((((q) ^ ((r) & 7)) * 8))

#define QSCALE 0.18033688011112042f   // 0.125 * log2(e); p = exp2(s) = exp(s/log2e)

__device__ __forceinline__ unsigned short bf16_rne(float f) {
    uint32_t u = __float_as_uint(f);
    u += 0x7FFFu + ((u >> 16) & 1u);
    return (unsigned short)(u >> 16);
}

__device__ __forceinline__ uint32_t pack_bf16x2(float a, float b) {
    __hip_bfloat162 h = __float22bfloat162_rn(float2{a, b});
    uint32_t r;
    memcpy(&r, &h, 4);
    return r;
}

__device__ __forceinline__ void split_bf16(float f, short& hi, short& lo) {
    uint32_t u = __float_as_uint(f);
    hi = (short)(u >> 16);
    float hif = __uint_as_float(u & 0xFFFF0000u);
    lo = (short)bf16_rne(f - hif);
}

__device__ __forceinline__ void async16(const void* g, void* l) {
    __builtin_amdgcn_global_load_lds(
        (__attribute__((address_space(1))) const uint32_t*)g,
        (__attribute__((address_space(3))) uint32_t*)l, 16, 0, 0);
}

// ---------------------------------------------------------------------------
// Fused pack (unchanged)
// ---------------------------------------------------------------------------
struct PackArgs {
    const float4* x;
    ushort4* xb;
    const float4* w[3];   // Wq, Wk, Wv
    ushort4* wb[3];
    const float4* wo;
    ushort4* woh;
    ushort4* wol;
};
__global__ __launch_bounds__(256) void pack_all(PackArgs a) {
    const int y = blockIdx.y;
    const int base = blockIdx.x * 256 + threadIdx.x;
    if (y == 0) {
#pragma unroll
        for (int it = 0; it < 4; ++it) {
            int i = base + it * 262144;
            float4 f = a.x[i];
            a.xb[i] = make_ushort4(bf16_rne(f.x), bf16_rne(f.y),
                                   bf16_rne(f.z), bf16_rne(f.w));
        }
    } else if (y <= 3) {
        int w = y - 1;
        float4 f = a.w[w][base];
        a.wb[w][base] = make_ushort4(bf16_rne(f.x), bf16_rne(f.y),
                                     bf16_rne(f.z), bf16_rne(f.w));
    } else {
        float4 f = a.wo[base];
        short h0, l0, h1, l1, h2, l2, h3, l3;
        split_bf16(f.x, h0, l0); split_bf16(f.y, h1, l1);
        split_bf16(f.z, h2, l2); split_bf16(f.w, h3, l3);
        a.woh[base] = make_ushort4(h0, h1, h2, h3);
        a.wol[base] = make_ushort4(l0, l1, l2, l3);
    }
}

// ---------------------------------------------------------------------------
// Fused QKV GEMM, R6: 256x128 tile, BK=64, 8 waves (4M x 2N, 64x64/wave),
// triple-buffered LDS (144 KB) with depth-2 prefetch and counted vmcnt(6):
//   per K-step: vmcnt(6); bar; 16 ds_read_b128; lgkmcnt(0); bar;
//               issue 6 stage loads for tile t+2; 32 MFMA (setprio 1).
// Loads never drain mid-loop -> full K-step of compute hides HBM latency.
// Epilogues copied verbatim from the verified R3 kernel (kappa^-1 V layout
// for the 16x16 attn, hds XOR for K, QSCALE for Q).
// Grid: dim3(24, 16) blocks of 512 thr; which = bx>>3.
// ---------------------------------------------------------------------------
#define QSTG(SB)                                                                \
    {                                                                           \
        async16(ga0, &sA[SB][(subA + 0) * 512]); ga0 += 64;                     \
        async16(ga1, &sA[SB][(subA + 1) * 512]); ga1 += 64;                     \
        async16(ga2, &sA[SB][(subA + 2) * 512]); ga2 += 64;                     \
        async16(ga3, &sA[SB][(subA + 3) * 512]); ga3 += 64;                     \
        async16(gb0, &sB[SB][(subB + 0) * 512]); gb0 += 64;                     \
        async16(gb1, &sB[SB][(subB + 1) * 512]); gb1 += 64;                     \
    }

#define QSTEP(C, SB, STG, VM)                                                   \
    {                                                                           \
        asm volatile("s_waitcnt vmcnt(" #VM ")" ::: "memory");                  \
        __builtin_amdgcn_s_barrier();                                           \
        __builtin_amdgcn_sched_barrier(0);                                      \
        short8 a_b[2][4], b_b[2][4];                                            \
        _Pragma("unroll")                                                       \
        for (int s2 = 0; s2 < 2; ++s2) {                                        \
            _Pragma("unroll")                                                   \
            for (int mi = 0; mi < 4; ++mi) {                                    \
                int r = wm * 64 + mi * 16 + col;                                \
                a_b[s2][mi] = *(const short8*)&sA[C][r * 64 + SWZ8(r, s2 * 4 + quad)]; \
            }                                                                   \
            _Pragma("unroll")                                                   \
            for (int ni = 0; ni < 4; ++ni) {                                    \
                int r = wn * 64 + ni * 16 + col;                                \
                b_b[s2][ni] = *(const short8*)&sB[C][r * 64 + SWZ8(r, s2 * 4 + quad)]; \
            }                                                                   \
        }                                                                       \
        asm volatile("s_waitcnt lgkmcnt(0)" ::: "memory");                      \
        __builtin_amdgcn_sched_barrier(0);                                      \
        __builtin_amdgcn_s_barrier();                                           \
        __builtin_amdgcn_sched_barrier(0);                                      \
        if (STG) QSTG(SB);                                                      \
        __builtin_amdgcn_s_setprio(1);                                          \
        if (which == 2) {                                                       \
            _Pragma("unroll")                                                   \
            for (int s2 = 0; s2 < 2; ++s2)                                      \
                _Pragma("unroll")                                               \
                for (int mi = 0; mi < 4; ++mi)                                  \
                    _Pragma("unroll")                                           \
                    for (int ni = 0; ni < 4; ++ni)                              \
                        acc[mi][ni] = MFMA16(a_b[s2][mi], b_b[s2][ni], acc[mi][ni], 0, 0, 0); \
        } else {                                                                \
            _Pragma("unroll")                                                   \
            for (int s2 = 0; s2 < 2; ++s2)                                      \
                _Pragma("unroll")                                               \
                for (int mi = 0; mi < 4; ++mi)                                  \
                    _Pragma("unroll")                                           \
                    for (int ni = 0; ni < 4; ++ni)                              \
                        acc[mi][ni] = MFMA16(b_b[s2][ni], a_b[s2][mi], acc[mi][ni], 0, 0, 0); \
        }                                                                       \
        __builtin_amdgcn_s_setprio(0);                                          \
    }

__global__ __launch_bounds__(512, 2) void gemm_qkv(
    const short* __restrict__ Xb,
    const short* __restrict__ Bq, const short* __restrict__ Bk,
    const short* __restrict__ Bv,
    short* __restrict__ Qo, short* __restrict__ Ko, short* __restrict__ Vo) {
    __shared__ short sA[3][256 * 64];   // 96 KB
    __shared__ short sB[3][128 * 64];   // 48 KB
    const int K = DMODEL;

    const int tid = threadIdx.x;
    const int lane = tid & 63, wave = tid >> 6;
    const int quad = lane >> 4, col = lane & 15;
    const int m0 = blockIdx.y * 256, n0 = blockIdx.x * 128;
    const int which = n0 >> 10;
    const int nn0 = n0 & 1023;
    const int wm = wave >> 1, wn = wave & 1;   // 4M x 2N -> 64x64 per wave

    const short* B = (which == 0) ? Bq : (which == 1) ? Bk : Bv;
    const short* Asrc = Xb + (size_t)m0 * K;
    const short* Bsrc = B + (size_t)nn0 * K;

    const int srow = lane >> 3;
    const int soff = (((lane & 7) ^ srow) * 8);

    // staging: wave stages A subs [wave*4, wave*4+4) and B subs [wave*2, wave*2+2)
    const int subA = wave * 4, subB = wave * 2;
    const short* ga0 = Asrc + (size_t)((subA + 0) * 8 + srow) * K + soff;
    const short* ga1 = Asrc + (size_t)((subA + 1) * 8 + srow) * K + soff;
    const short* ga2 = Asrc + (size_t)((subA + 2) * 8 + srow) * K + soff;
    const short* ga3 = Asrc + (size_t)((subA + 3) * 8 + srow) * K + soff;
    const short* gb0 = Bsrc + (size_t)((subB + 0) * 8 + srow) * K + soff;
    const short* gb1 = Bsrc + (size_t)((subB + 1) * 8 + srow) * K + soff;

    floatx4 acc[4][4] = {};

    // prologue: tiles 0 and 1
    QSTG(0);
    QSTG(1);

    // 16 K-steps, period-3 buffer rotation, stage t+2 while computing t
    QSTEP(0, 2, 1, 6);  // t=0
    QSTEP(1, 0, 1, 6);  // t=1
    QSTEP(2, 1, 1, 6);  // t=2
    QSTEP(0, 2, 1, 6);  // t=3
    QSTEP(1, 0, 1, 6);  // t=4
    QSTEP(2, 1, 1, 6);  // t=5
    QSTEP(0, 2, 1, 6);  // t=6
    QSTEP(1, 0, 1, 6);  // t=7
    QSTEP(2, 1, 1, 6);  // t=8
    QSTEP(0, 2, 1, 6);  // t=9
    QSTEP(1, 0, 1, 6);  // t=10
    QSTEP(2, 1, 1, 6);  // t=11
    QSTEP(0, 2, 1, 6);  // t=12
    QSTEP(1, 0, 1, 6);  // t=13  (stages tile 15, the last)
    QSTEP(2, 1, 0, 6);  // t=14  (no stage)
    QSTEP(0, 2, 0, 0);  // t=15  (no stage, full drain)

    const int mb = m0 + wm * 64;
    const int nlb = nn0 + wn * 64;
    if (which == 2) {
        // V^T [bh][hd][t], kappa-permuted window position + chunk-XOR swizzle
#pragma unroll
        for (int ni = 0; ni < 4; ++ni) {
            int n = nlb + ni * 16 + col;
            int h = n >> 6, hd = n & 63;
#pragma unroll
            for (int mi = 0; mi < 4; ++mi) {
                int m4 = mb + mi * 16 + quad * 4;
                int b = m4 >> 11, t0 = m4 & 2047;
                // kappa^-1: key bits [t5][t4][t3t2][t1t0] -> s = [t5][t3t2][t4][t1t0]
                int sw = (t0 & 32) | ((t0 & 12) << 1) | ((t0 & 16) >> 2);
                int tsw = (t0 & ~63) | ((((sw >> 3) ^ (hd & 7)) << 3) | (sw & 7));
                size_t row = ((size_t)(b * NH + h) * HD + hd) * TSEQ;
                *(ushort4*)&Vo[row + tsw] =
                    make_ushort4(bf16_rne(acc[mi][ni][0]), bf16_rne(acc[mi][ni][1]),
                                 bf16_rne(acc[mi][ni][2]), bf16_rne(acc[mi][ni][3]));
            }
        }
    } else {
        short* O = (which == 0) ? Qo : Ko;
        const float sc = (which == 0) ? QSCALE : 1.0f;
#pragma unroll
        for (int mi = 0; mi < 4; ++mi) {
            int m = mb + mi * 16 + col;
            int b = m >> 11, t = m & 2047;
#pragma unroll
            for (int ni = 0; ni < 4; ++ni) {
                int n = nlb + ni * 16 + quad * 4;
                int h = n >> 6, hd = n & 63;
                int hds = (which == 1) ? ((((hd >> 3) ^ (t & 7)) << 3) | (hd & 7)) : hd;
                size_t idx = ((size_t)(b * NH + h) * TSEQ + t) * HD + hds;
                *(ushort4*)&O[idx] =
                    make_ushort4(bf16_rne(acc[mi][ni][0] * sc), bf16_rne(acc[mi][ni][1] * sc),
                                 bf16_rne(acc[mi][ni][2] * sc), bf16_rne(acc[mi][ni][3] * sc));
            }
        }
    }
}

// ---------------------------------------------------------------------------
// Flash attention — exact R3 revert (best measured: 50.4 us).
// 512 thr = 8 waves, 16 q/wave, 128 keys/round; dbuf K/V LDS; counted
// vmcnt(4); ones-MFMA l accumulation; imm-offset LDS reads; setprio.
// ---------------------------------------------------------------------------
#define ATTN_COMPUTE(DB)                                                        \
    {                                                                           \
        _Pragma("unroll")                                                       \
        for (int u = 0; u < 2; ++u) {                                           \
            floatx4 s[4] = {};                                                  \
            __builtin_amdgcn_s_setprio(1);                                      \
            _Pragma("unroll")                                                   \
            for (int k4 = 0; k4 < 4; ++k4) {                                    \
                short8 kf0 = *(const short8*)(kb0 + (DB) * 8192 + u * 4096 + k4 * 1024); \
                short8 kf1 = *(const short8*)(kb1 + (DB) * 8192 + u * 4096 + k4 * 1024); \
                s[k4] = MFMA16(kf0, qf[0], s[k4], 0, 0, 0);                     \
                s[k4] = MFMA16(kf1, qf[1], s[k4], 0, 0, 0);                     \
            }                                                                   \
            __builtin_amdgcn_s_setprio(0);                                      \
            float p[4][4];                                                      \
            _Pragma("unroll")                                                   \
            for (int k4 = 0; k4 < 4; ++k4)                                      \
                _Pragma("unroll")                                               \
                for (int r4 = 0; r4 < 4; ++r4)                                  \
                    p[k4][r4] = __builtin_amdgcn_exp2f(s[k4][r4]);              \
            _Pragma("unroll")                                                   \
            for (int c = 0; c < 2; ++c) {                                       \
                union { short8 v; uint32_t w[4]; } pf;                          \
                pf.w[0] = pack_bf16x2(p[2 * c][0], p[2 * c][1]);                \
                pf.w[1] = pack_bf16x2(p[2 * c][2], p[2 * c][3]);                \
                pf.w[2] = pack_bf16x2(p[2 * c + 1][0], p[2 * c + 1][1]);        \
                pf.w[3] = pack_bf16x2(p[2 * c + 1][2], p[2 * c + 1][3]);        \
                const short* vbc = c ? vb1 : vb0;                               \
                __builtin_amdgcn_s_setprio(1);                                  \
                lacc = MFMA16(ones.v, pf.v, lacc, 0, 0, 0);                     \
                _Pragma("unroll")                                               \
                for (int ni = 0; ni < 4; ++ni) {                                \
                    short8 vf = *(const short8*)(vbc + (DB) * 8192 + u * 4096 + ni * 1024); \
                    O[ni] = MFMA16(vf, pf.v, O[ni], 0, 0, 0);                   \
                }                                                               \
                __builtin_amdgcn_s_setprio(0);                                  \
            }                                                                   \
        }                                                                       \
    }

#define ASTAGE(LB)                                                              \
    {                                                                           \
        async16(g0, (LB) + 0 * 512);                                            \
        async16(g1, (LB) + 1 * 512);                                            \
        async16(g2, (LB) + 2 * 512);                                            \
        async16(g3, (LB) + 3 * 512);                                            \
        g0 += ktstep; g1 += ktstep; g2 += ktstep; g3 += ktstep;                 \
    }

__global__ __launch_bounds__(512, 4) void attn_bf16(
    const short* __restrict__ Qb, const short* __restrict__ Kb,
    const short* __restrict__ Vb, short* __restrict__ Cb) {
    __shared__ short sK[2][2][64 * 64];   // [dbuf][tile]
    __shared__ short sV[2][2][64 * 64];

    const int tid = threadIdx.x;
    const int lane = tid & 63, wave = tid >> 6;
    const int quad = lane >> 4, col = lane & 15;
    const int qt = blockIdx.x, bh = blockIdx.y;
    const size_t bhoff = (size_t)bh * TSEQ * HD;

    // Q as B-operand frags: B[n=q=col][k=quad*8+j]
    const size_t qrow = (size_t)(qt * 128 + wave * 16 + col) * HD;
    short8 qf[2];
#pragma unroll
    for (int c = 0; c < 2; ++c)
        qf[c] = *(const short8*)&Qb[bhoff + qrow + c * 32 + quad * 8];

    const int srow = lane >> 3;
    const int schunk = (lane & 7) * 8;   // K/V globally pre-swizzled

    // staging geometry: wave w stages 4 slots n = w*4 + j
    const int isV = wave >> 2;
    const int tl = (wave >> 1) & 1;
    const int sb = (wave & 1) * 4;

    const short *g0, *g1, *g2, *g3;
    size_t ktstep;
    if (!isV) {
        g0 = Kb + bhoff + (size_t)(tl * 64 + (sb + 0) * 8 + srow) * HD + schunk;
        g1 = Kb + bhoff + (size_t)(tl * 64 + (sb + 1) * 8 + srow) * HD + schunk;
        g2 = Kb + bhoff + (size_t)(tl * 64 + (sb + 2) * 8 + srow) * HD + schunk;
        g3 = Kb + bhoff + (size_t)(tl * 64 + (sb + 3) * 8 + srow) * HD + schunk;
        ktstep = (size_t)128 * HD;
    } else {
        g0 = Vb + bhoff + (size_t)((sb + 0) * 8 + srow) * TSEQ + tl * 64 + schunk;
        g1 = Vb + bhoff + (size_t)((sb + 1) * 8 + srow) * TSEQ + tl * 64 + schunk;
        g2 = Vb + bhoff + (size_t)((sb + 2) * 8 + srow) * TSEQ + tl * 64 + schunk;
        g3 = Vb + bhoff + (size_t)((sb + 3) * 8 + srow) * TSEQ + tl * 64 + schunk;
        ktstep = 128;
    }
    short* lb0_ = isV ? &sV[0][tl][sb * 512] : &sK[0][tl][sb * 512];
    short* lb1_ = isV ? &sV[1][tl][sb * 512] : &sK[1][tl][sb * 512];

    // LDS fragment-read bases: all ds_reads are base + compile-time imm.
    const int ch0 = ((quad ^ (col & 7)) << 3);
    const int ch1 = (((4 + quad) ^ (col & 7)) << 3);
    const short* kb0 = &sK[0][0][col * 64 + ch0];
    const short* kb1 = &sK[0][0][col * 64 + ch1];
    const short* vb0 = &sV[0][0][col * 64 + ch0];
    const short* vb1 = &sV[0][0][col * 64 + ch1];

    // bf16 1.0 x8 for the l-accumulating MFMA
    union { short8 v; short s[8]; } ones;
#pragma unroll
    for (int j = 0; j < 8; ++j) ones.s[j] = (short)0x3F80;

    floatx4 lacc = {};      // every element = running l for q = col
    floatx4 O[4] = {};      // O^T: hd = ni*16 + quad*4 + r, q = col

    ASTAGE(lb0_);           // tile 0 -> db0

    for (int kt2 = 0; kt2 < 8; ++kt2) {
        ASTAGE(lb1_);
        asm volatile("s_waitcnt vmcnt(4)" ::: "memory");
        __builtin_amdgcn_s_barrier();
        ATTN_COMPUTE(0);
        __builtin_amdgcn_s_barrier();

        if (kt2 < 7) {
            ASTAGE(lb0_);
            asm volatile("s_waitcnt vmcnt(4)" ::: "memory");
        } else {
            asm volatile("s_waitcnt vmcnt(0)" ::: "memory");
        }
        __builtin_amdgcn_s_barrier();
        ATTN_COMPUTE(1);
        __builtin_amdgcn_s_barrier();
    }

    // l is fully summed over all keys by the ones-MFMA (B-layout spans k=0..31)
    const float inv = 1.0f / lacc[0];

    const int b = bh >> 4, h = bh & 15;
    const int trow = qt * 128 + wave * 16 + col;
    const size_t obase = (size_t)(b * TSEQ + trow) * DMODEL + h * 64;
#pragma unroll
    for (int ni = 0; ni < 4; ++ni) {
        uint2 pk;
        pk.x = pack_bf16x2(O[ni][0] * inv, O[ni][1] * inv);
        pk.y = pack_bf16x2(O[ni][2] * inv, O[ni][3] * inv);
        *(uint2*)&Cb[obase + ni * 16 + quad * 4] = pk;
    }
}

// ---------------------------------------------------------------------------
// Out-proj 2-term, operand-flipped (unchanged). 128x64, BK=64.
// ---------------------------------------------------------------------------
__global__ __launch_bounds__(256) void gemm_out(
    const short* __restrict__ Ab,
    const short* __restrict__ Bh, const short* __restrict__ Bl,
    const float* __restrict__ bias, float* __restrict__ Of) {
    __shared__ short sA[128 * 64];
    __shared__ short sBh[64 * 64];
    __shared__ short sBl[64 * 64];
    const int K = DMODEL, N = DMODEL;

    const int tid = threadIdx.x;
    const int lane = tid & 63, wave = tid >> 6;
    const int quad = lane >> 4, col = lane & 15;
    const int m0 = blockIdx.y * 128, n0 = blockIdx.x * 64;
    const int wm = wave >> 1, wn = wave & 1;

    const short* Asrc = Ab + (size_t)m0 * K;
    const short* Bhsrc = Bh + (size_t)n0 * K;
    const short* Blsrc = Bl + (size_t)n0 * K;
    const int srow = lane >> 3;
    const int soff = (((lane & 7) ^ srow) * 8);

    floatx4 acc[4][2] = {};

    for (int k0 = 0; k0 < K; k0 += 64) {
        __syncthreads();
#pragma unroll
        for (int j = 0; j < 8; ++j) {
            int idx = wave * 8 + j;
            int buf = (idx < 16) ? 0 : (idx < 24) ? 1 : 2;
            int sub = (buf == 0) ? idx : (buf == 1) ? idx - 16 : idx - 24;
            const short* s = (buf == 0) ? Asrc : (buf == 1) ? Bhsrc : Blsrc;
            short* d = (buf == 0) ? sA : (buf == 1) ? sBh : sBl;
            async16(s + (size_t)(sub * 8 + srow) * K + k0 + soff, d + sub * 512);
        }
        __syncthreads();

#pragma unroll
        for (int s2 = 0; s2 < 2; ++s2) {
            short8 a_b[4], b_h[2], b_l[2];
#pragma unroll
            for (int mi = 0; mi < 4; ++mi) {
                int r = wm * 64 + mi * 16 + col;
                a_b[mi] = *(const short8*)&sA[r * 64 + SWZ8(r, s2 * 4 + quad)];
            }
#pragma unroll
            for (int ni = 0; ni < 2; ++ni) {
                int r = wn * 32 + ni * 16 + col;
                b_h[ni] = *(const short8*)&sBh[r * 64 + SWZ8(r, s2 * 4 + quad)];
                b_l[ni] = *(const short8*)&sBl[r * 64 + SWZ8(r, s2 * 4 + quad)];
            }
#pragma unroll
            for (int mi = 0; mi < 4; ++mi)
#pragma unroll
                for (int ni = 0; ni < 2; ++ni) {
                    acc[mi][ni] = MFMA16(b_h[ni], a_b[mi], acc[mi][ni], 0, 0, 0);
                    acc[mi][ni] = MFMA16(b_l[ni], a_b[mi], acc[mi][ni], 0, 0, 0);
                }
        }
    }

    const int mb = m0 + wm * 64, nb = n0 + wn * 32;
#pragma unroll
    for (int mi = 0; mi < 4; ++mi) {
        int m = mb + mi * 16 + col;
#pragma unroll
        for (int ni = 0; ni < 2; ++ni) {
            int n = nb + ni * 16 + quad * 4;
            float4 bv = *(const float4*)&bias[n];
            float4 o = make_float4(acc[mi][ni][0] + bv.x, acc[mi][ni][1] + bv.y,
                                   acc[mi][ni][2] + bv.z, acc[mi][ni][3] + bv.w);
            *(float4*)&Of[(size_t)m * N + n] = o;
        }
    }
}

// ---------------------------------------------------------------------------
extern "C" void kernel_launch(void* const* d_in, const int* in_sizes, int n_in,
                              void* d_out, int out_size, void* d_ws, size_t ws_size,
                              hipStream_t stream) {
    const float* x  = (const float*)d_in[0];
    const float* Wq = (const float*)d_in[1];
    const float* Wk = (const float*)d_in[2];
    const float* Wv = (const float*)d_in[3];
    const float* Wo = (const float*)d_in[4];
    const float* bo = (const float*)d_in[5];
    float* out = (float*)d_out;

    const size_t NX = (size_t)BROWS * DMODEL;   // 4M
    const size_t NW = (size_t)DMODEL * DMODEL;  // 1M
    short* p = (short*)d_ws;
    short *xb = p;
    short *wqb = xb + NX;
    short *wkb = wqb + NW;
    short *wvb = wkb + NW;
    short *woh = wvb + NW; short *wol = woh + NW;
    short *qb = wol + NW;
    short *kb = qb + NX;
    short *vb = kb + NX;
    short *cb = vb + NX;

    PackArgs pa;
    pa.x = (const float4*)x; pa.xb = (ushort4*)xb;
    pa.w[0] = (const float4*)Wq; pa.wb[0] = (ushort4*)wqb;
    pa.w[1] = (const float4*)Wk; pa.wb[1] = (ushort4*)wkb;
    pa.w[2] = (const float4*)Wv; pa.wb[2] = (ushort4*)wvb;
    pa.wo = (const float4*)Wo; pa.woh = (ushort4*)woh; pa.wol = (ushort4*)wol;
    pack_all<<<dim3(1024, 5), dim3(256), 0, stream>>>(pa);

    gemm_qkv<<<dim3(3 * DMODEL / 128, BROWS / 256), dim3(512), 0, stream>>>(
        xb, wqb, wkb, wvb, qb, kb, vb);

    attn_bf16<<<dim3(TSEQ / 128, BH), dim3(512), 0, stream>>>(qb, kb, vb, cb);

    gemm_out<<<dim3(DMODEL / 64, BROWS / 128), dim3(256), 0, stream>>>(cb, woh, wol, bo, out);
}

// Round 7
// 182.967 us; speedup vs baseline: 1.1072x; 1.0426x over previous
//
#include <hip/hip_runtime.h>
#include <hip/hip_bf16.h>
#include <math.h>
#include <stdint.h>
#include <string.h>

#define TSEQ 2048
#define DMODEL 1024
#define NH 16
#define HD 64
#define BROWS 4096   // b*t
#define BH 32        // b*h

typedef __attribute__((ext_vector_type(8))) short short8;
typedef __attribute__((ext_vector_type(4))) float floatx4;

#define MFMA16 __builtin_amdgcn_mfma_f32_16x16x32_bf16
// 3-bit chunk-XOR swizzle on 64-short (128 B) rows
#define SWZ8(r, q) ((((q) ^ ((r) & 7)) * 8))

#define QSCALE 0.18033688011112042f   // 0.125 * log2(e); p = exp2(s) = exp(s/log2e)

__device__ __forceinline__ unsigned short bf16_rne(float f) {
    uint32_t u = __float_as_uint(f);
    u += 0x7FFFu + ((u >> 16) & 1u);
    return (unsigned short)(u >> 16);
}

__device__ __forceinline__ uint32_t pack_bf16x2(float a, float b) {
    __hip_bfloat162 h = __float22bfloat162_rn(float2{a, b});
    uint32_t r;
    memcpy(&r, &h, 4);
    return r;
}

__device__ __forceinline__ void split_bf16(float f, short& hi, short& lo) {
    uint32_t u = __float_as_uint(f);
    hi = (short)(u >> 16);
    float hif = __uint_as_float(u & 0xFFFF0000u);
    lo = (short)bf16_rne(f - hif);
}

__device__ __forceinline__ void async16(const void* g, void* l) {
    __builtin_amdgcn_global_load_lds(
        (__attribute__((address_space(1))) const uint32_t*)g,
        (__attribute__((address_space(3))) uint32_t*)l, 16, 0, 0);
}

// ---------------------------------------------------------------------------
// Fused pack (unchanged)
// ---------------------------------------------------------------------------
struct PackArgs {
    const float4* x;
    ushort4* xb;
    const float4* w[3];   // Wq, Wk, Wv
    ushort4* wb[3];
    const float4* wo;
    ushort4* woh;
    ushort4* wol;
};
__global__ __launch_bounds__(256) void pack_all(PackArgs a) {
    const int y = blockIdx.y;
    const int base = blockIdx.x * 256 + threadIdx.x;
    if (y == 0) {
#pragma unroll
        for (int it = 0; it < 4; ++it) {
            int i = base + it * 262144;
            float4 f = a.x[i];
            a.xb[i] = make_ushort4(bf16_rne(f.x), bf16_rne(f.y),
                                   bf16_rne(f.z), bf16_rne(f.w));
        }
    } else if (y <= 3) {
        int w = y - 1;
        float4 f = a.w[w][base];
        a.wb[w][base] = make_ushort4(bf16_rne(f.x), bf16_rne(f.y),
                                     bf16_rne(f.z), bf16_rne(f.w));
    } else {
        float4 f = a.wo[base];
        short h0, l0, h1, l1, h2, l2, h3, l3;
        split_bf16(f.x, h0, l0); split_bf16(f.y, h1, l1);
        split_bf16(f.z, h2, l2); split_bf16(f.w, h3, l3);
        a.woh[base] = make_ushort4(h0, h1, h2, h3);
        a.wol[base] = make_ushort4(l0, l1, l2, l3);
    }
}

// ---------------------------------------------------------------------------
// Fused QKV GEMM, R7: 128x128, BK=64, 256 thr / 4 waves, DOUBLE-buffered LDS
// (64 KB -> 2 blocks/CU) with counted vmcnt(8): stage tile t+1 while
// computing t; loads stay in flight across barriers (R1-proven schedule).
// XCD swizzle: each XCD owns a 3-wide n-stripe (768 KB of B fits 4MB L2).
// Epilogues verbatim from the verified R3 kernel.
// ---------------------------------------------------------------------------
#define QSTAGE(DB, K0)                                                          \
    {                                                                           \
        _Pragma("unroll")                                                       \
        for (int j = 0; j < 8; ++j) {                                           \
            int idx = wave * 8 + j;                                             \
            int sub = idx & 15;                                                 \
            const short* s = (idx < 16) ? Asrc : Bsrc;                          \
            short* d = (idx < 16) ? sA[DB] : sB[DB];                            \
            async16(s + (size_t)(sub * 8 + srow) * K + (K0) + soff, d + sub * 512); \
        }                                                                       \
    }

__global__ __launch_bounds__(256) void gemm_qkv(
    const short* __restrict__ Xb,
    const short* __restrict__ Bq, const short* __restrict__ Bk,
    const short* __restrict__ Bv,
    short* __restrict__ Qo, short* __restrict__ Ko, short* __restrict__ Vo) {
    __shared__ short sA[2][128 * 64];
    __shared__ short sB[2][128 * 64];
    const int K = DMODEL;

    const int tid = threadIdx.x;
    const int lane = tid & 63, wave = tid >> 6;
    const int quad = lane >> 4, col = lane & 15;

    // XCD swizzle: lin = by*24+bx; xcd owns bx' = 3*xcd + (j%3), all by'
    const int lin = blockIdx.y * 24 + blockIdx.x;
    const int xcd = lin & 7, j8 = lin >> 3;          // j8 in [0,96)
    const int bxp = 3 * xcd + (j8 % 3);
    const int byp = j8 / 3;
    const int m0 = byp * 128, n0 = bxp * 128;
    const int which = n0 >> 10;
    const int nn0 = n0 & 1023;
    const int wm = wave >> 1, wn = wave & 1;

    const short* B = (which == 0) ? Bq : (which == 1) ? Bk : Bv;
    const short* Asrc = Xb + (size_t)m0 * K;
    const short* Bsrc = B + (size_t)nn0 * K;

    const int srow = lane >> 3;
    const int soff = (((lane & 7) ^ srow) * 8);

    floatx4 acc[4][4] = {};

    QSTAGE(0, 0);
    for (int t = 0; t < 16; ++t) {
        const int db = t & 1;
        if (t < 15) {
            QSTAGE(db ^ 1, (t + 1) * 64);
            asm volatile("s_waitcnt vmcnt(8)" ::: "memory");
        } else {
            asm volatile("s_waitcnt vmcnt(0)" ::: "memory");
        }
        __builtin_amdgcn_s_barrier();

#pragma unroll
        for (int s2 = 0; s2 < 2; ++s2) {
            short8 a_b[4], b_b[4];
#pragma unroll
            for (int mi = 0; mi < 4; ++mi) {
                int r = wm * 64 + mi * 16 + col;
                a_b[mi] = *(const short8*)&sA[db][r * 64 + SWZ8(r, s2 * 4 + quad)];
            }
#pragma unroll
            for (int ni = 0; ni < 4; ++ni) {
                int r = wn * 64 + ni * 16 + col;
                b_b[ni] = *(const short8*)&sB[db][r * 64 + SWZ8(r, s2 * 4 + quad)];
            }
            __builtin_amdgcn_s_setprio(1);
            if (which == 2) {
#pragma unroll
                for (int mi = 0; mi < 4; ++mi)
#pragma unroll
                    for (int ni = 0; ni < 4; ++ni)
                        acc[mi][ni] = MFMA16(a_b[mi], b_b[ni], acc[mi][ni], 0, 0, 0);
            } else {
#pragma unroll
                for (int mi = 0; mi < 4; ++mi)
#pragma unroll
                    for (int ni = 0; ni < 4; ++ni)
                        acc[mi][ni] = MFMA16(b_b[ni], a_b[mi], acc[mi][ni], 0, 0, 0);
            }
            __builtin_amdgcn_s_setprio(0);
        }
        __builtin_amdgcn_s_barrier();
    }

    const int mb = m0 + wm * 64;
    const int nlb = nn0 + wn * 64;
    if (which == 2) {
        // V^T [bh][hd][t], kappa-permuted window position + chunk-XOR swizzle
#pragma unroll
        for (int ni = 0; ni < 4; ++ni) {
            int n = nlb + ni * 16 + col;
            int h = n >> 6, hd = n & 63;
#pragma unroll
            for (int mi = 0; mi < 4; ++mi) {
                int m4 = mb + mi * 16 + quad * 4;
                int b = m4 >> 11, t0 = m4 & 2047;
                // kappa^-1: key bits [t5][t4][t3t2][t1t0] -> s = [t5][t3t2][t4][t1t0]
                int sw = (t0 & 32) | ((t0 & 12) << 1) | ((t0 & 16) >> 2);
                int tsw = (t0 & ~63) | ((((sw >> 3) ^ (hd & 7)) << 3) | (sw & 7));
                size_t row = ((size_t)(b * NH + h) * HD + hd) * TSEQ;
                *(ushort4*)&Vo[row + tsw] =
                    make_ushort4(bf16_rne(acc[mi][ni][0]), bf16_rne(acc[mi][ni][1]),
                                 bf16_rne(acc[mi][ni][2]), bf16_rne(acc[mi][ni][3]));
            }
        }
    } else {
        short* O = (which == 0) ? Qo : Ko;
        const float sc = (which == 0) ? QSCALE : 1.0f;
#pragma unroll
        for (int mi = 0; mi < 4; ++mi) {
            int m = mb + mi * 16 + col;
            int b = m >> 11, t = m & 2047;
#pragma unroll
            for (int ni = 0; ni < 4; ++ni) {
                int n = nlb + ni * 16 + quad * 4;
                int h = n >> 6, hd = n & 63;
                int hds = (which == 1) ? ((((hd >> 3) ^ (t & 7)) << 3) | (hd & 7)) : hd;
                size_t idx = ((size_t)(b * NH + h) * TSEQ + t) * HD + hds;
                *(ushort4*)&O[idx] =
                    make_ushort4(bf16_rne(acc[mi][ni][0] * sc), bf16_rne(acc[mi][ni][1] * sc),
                                 bf16_rne(acc[mi][ni][2] * sc), bf16_rne(acc[mi][ni][3] * sc));
            }
        }
    }
}

// ---------------------------------------------------------------------------
// Flash attention — R3 structure (50.4 us verified) + XCD swizzle:
// each XCD owns 4 consecutive bh (K/V = 2 MB, fits 4 MB L2).
// ---------------------------------------------------------------------------
#define ATTN_COMPUTE(DB)                                                        \
    {                                                                           \
        _Pragma("unroll")                                                       \
        for (int u = 0; u < 2; ++u) {                                           \
            floatx4 s[4] = {};                                                  \
            __builtin_amdgcn_s_setprio(1);                                      \
            _Pragma("unroll")                                                   \
            for (int k4 = 0; k4 < 4; ++k4) {                                    \
                short8 kf0 = *(const short8*)(kb0 + (DB) * 8192 + u * 4096 + k4 * 1024); \
                short8 kf1 = *(const short8*)(kb1 + (DB) * 8192 + u * 4096 + k4 * 1024); \
                s[k4] = MFMA16(kf0, qf[0], s[k4], 0, 0, 0);                     \
                s[k4] = MFMA16(kf1, qf[1], s[k4], 0, 0, 0);                     \
            }                                                                   \
            __builtin_amdgcn_s_setprio(0);                                      \
            float p[4][4];                                                      \
            _Pragma("unroll")                                                   \
            for (int k4 = 0; k4 < 4; ++k4)                                      \
                _Pragma("unroll")                                               \
                for (int r4 = 0; r4 < 4; ++r4)                                  \
                    p[k4][r4] = __builtin_amdgcn_exp2f(s[k4][r4]);              \
            _Pragma("unroll")                                                   \
            for (int c = 0; c < 2; ++c) {                                       \
                union { short8 v; uint32_t w[4]; } pf;                          \
                pf.w[0] = pack_bf16x2(p[2 * c][0], p[2 * c][1]);                \
                pf.w[1] = pack_bf16x2(p[2 * c][2], p[2 * c][3]);                \
                pf.w[2] = pack_bf16x2(p[2 * c + 1][0], p[2 * c + 1][1]);        \
                pf.w[3] = pack_bf16x2(p[2 * c + 1][2], p[2 * c + 1][3]);        \
                const short* vbc = c ? vb1 : vb0;                               \
                __builtin_amdgcn_s_setprio(1);                                  \
                lacc = MFMA16(ones.v, pf.v, lacc, 0, 0, 0);                     \
                _Pragma("unroll")                                               \
                for (int ni = 0; ni < 4; ++ni) {                                \
                    short8 vf = *(const short8*)(vbc + (DB) * 8192 + u * 4096 + ni * 1024); \
                    O[ni] = MFMA16(vf, pf.v, O[ni], 0, 0, 0);                   \
                }                                                               \
                __builtin_amdgcn_s_setprio(0);                                  \
            }                                                                   \
        }                                                                       \
    }

#define ASTAGE(LB)                                                              \
    {                                                                           \
        async16(g0, (LB) + 0 * 512);                                            \
        async16(g1, (LB) + 1 * 512);                                            \
        async16(g2, (LB) + 2 * 512);                                            \
        async16(g3, (LB) + 3 * 512);                                            \
        g0 += ktstep; g1 += ktstep; g2 += ktstep; g3 += ktstep;                 \
    }

__global__ __launch_bounds__(512, 4) void attn_bf16(
    const short* __restrict__ Qb, const short* __restrict__ Kb,
    const short* __restrict__ Vb, short* __restrict__ Cb) {
    __shared__ short sK[2][2][64 * 64];   // [dbuf][tile]
    __shared__ short sV[2][2][64 * 64];

    const int tid = threadIdx.x;
    const int lane = tid & 63, wave = tid >> 6;
    const int quad = lane >> 4, col = lane & 15;

    // XCD swizzle: lin in [0,512); XCD xcd handles bh in {4*xcd..4*xcd+3}
    const int lin = blockIdx.y * 16 + blockIdx.x;
    const int xcd = lin & 7, j8 = lin >> 3;          // j8 in [0,64)
    const int qt = j8 & 15;
    const int bh = 4 * xcd + (j8 >> 4);
    const size_t bhoff = (size_t)bh * TSEQ * HD;

    // Q as B-operand frags: B[n=q=col][k=quad*8+j]
    const size_t qrow = (size_t)(qt * 128 + wave * 16 + col) * HD;
    short8 qf[2];
#pragma unroll
    for (int c = 0; c < 2; ++c)
        qf[c] = *(const short8*)&Qb[bhoff + qrow + c * 32 + quad * 8];

    const int srow = lane >> 3;
    const int schunk = (lane & 7) * 8;   // K/V globally pre-swizzled

    // staging geometry: wave w stages 4 slots n = w*4 + j
    const int isV = wave >> 2;
    const int tl = (wave >> 1) & 1;
    const int sb = (wave & 1) * 4;

    const short *g0, *g1, *g2, *g3;
    size_t ktstep;
    if (!isV) {
        g0 = Kb + bhoff + (size_t)(tl * 64 + (sb + 0) * 8 + srow) * HD + schunk;
        g1 = Kb + bhoff + (size_t)(tl * 64 + (sb + 1) * 8 + srow) * HD + schunk;
        g2 = Kb + bhoff + (size_t)(tl * 64 + (sb + 2) * 8 + srow) * HD + schunk;
        g3 = Kb + bhoff + (size_t)(tl * 64 + (sb + 3) * 8 + srow) * HD + schunk;
        ktstep = (size_t)128 * HD;
    } else {
        g0 = Vb + bhoff + (size_t)((sb + 0) * 8 + srow) * TSEQ + tl * 64 + schunk;
        g1 = Vb + bhoff + (size_t)((sb + 1) * 8 + srow) * TSEQ + tl * 64 + schunk;
        g2 = Vb + bhoff + (size_t)((sb + 2) * 8 + srow) * TSEQ + tl * 64 + schunk;
        g3 = Vb + bhoff + (size_t)((sb + 3) * 8 + srow) * TSEQ + tl * 64 + schunk;
        ktstep = 128;
    }
    short* lb0_ = isV ? &sV[0][tl][sb * 512] : &sK[0][tl][sb * 512];
    short* lb1_ = isV ? &sV[1][tl][sb * 512] : &sK[1][tl][sb * 512];

    // LDS fragment-read bases: all ds_reads are base + compile-time imm.
    const int ch0 = ((quad ^ (col & 7)) << 3);
    const int ch1 = (((4 + quad) ^ (col & 7)) << 3);
    const short* kb0 = &sK[0][0][col * 64 + ch0];
    const short* kb1 = &sK[0][0][col * 64 + ch1];
    const short* vb0 = &sV[0][0][col * 64 + ch0];
    const short* vb1 = &sV[0][0][col * 64 + ch1];

    // bf16 1.0 x8 for the l-accumulating MFMA
    union { short8 v; short s[8]; } ones;
#pragma unroll
    for (int j = 0; j < 8; ++j) ones.s[j] = (short)0x3F80;

    floatx4 lacc = {};      // every element = running l for q = col
    floatx4 O[4] = {};      // O^T: hd = ni*16 + quad*4 + r, q = col

    ASTAGE(lb0_);           // tile 0 -> db0

    for (int kt2 = 0; kt2 < 8; ++kt2) {
        ASTAGE(lb1_);
        asm volatile("s_waitcnt vmcnt(4)" ::: "memory");
        __builtin_amdgcn_s_barrier();
        ATTN_COMPUTE(0);
        __builtin_amdgcn_s_barrier();

        if (kt2 < 7) {
            ASTAGE(lb0_);
            asm volatile("s_waitcnt vmcnt(4)" ::: "memory");
        } else {
            asm volatile("s_waitcnt vmcnt(0)" ::: "memory");
        }
        __builtin_amdgcn_s_barrier();
        ATTN_COMPUTE(1);
        __builtin_amdgcn_s_barrier();
    }

    // l is fully summed over all keys by the ones-MFMA (B-layout spans k=0..31)
    const float inv = 1.0f / lacc[0];

    const int b = bh >> 4, h = bh & 15;
    const int trow = qt * 128 + wave * 16 + col;
    const size_t obase = (size_t)(b * TSEQ + trow) * DMODEL + h * 64;
#pragma unroll
    for (int ni = 0; ni < 4; ++ni) {
        uint2 pk;
        pk.x = pack_bf16x2(O[ni][0] * inv, O[ni][1] * inv);
        pk.y = pack_bf16x2(O[ni][2] * inv, O[ni][3] * inv);
        *(uint2*)&Cb[obase + ni * 16 + quad * 4] = pk;
    }
}

// ---------------------------------------------------------------------------
// Out-proj 2-term, R7: dbuf LDS (64 KB) + counted vmcnt(8), XCD swizzle
// (each XCD owns a 2-wide n-stripe: 512 KB of Bh+Bl in L2).
// ---------------------------------------------------------------------------
#define OSTAGE(DB, K0)                                                          \
    {                                                                           \
        _Pragma("unroll")                                                       \
        for (int j = 0; j < 8; ++j) {                                           \
            int idx = wave * 8 + j;                                             \
            int buf = (idx < 16) ? 0 : (idx < 24) ? 1 : 2;                      \
            int sub = (buf == 0) ? idx : (buf == 1) ? idx - 16 : idx - 24;      \
            const short* s = (buf == 0) ? Asrc : (buf == 1) ? Bhsrc : Blsrc;    \
            short* d = (buf == 0) ? sA[DB] : (buf == 1) ? sBh[DB] : sBl[DB];    \
            async16(s + (size_t)(sub * 8 + srow) * K + (K0) + soff, d + sub * 512); \
        }                                                                       \
    }

__global__ __launch_bounds__(256) void gemm_out(
    const short* __restrict__ Ab,
    const short* __restrict__ Bh, const short* __restrict__ Bl,
    const float* __restrict__ bias, float* __restrict__ Of) {
    __shared__ short sA[2][128 * 64];
    __shared__ short sBh[2][64 * 64];
    __shared__ short sBl[2][64 * 64];
    const int K = DMODEL, N = DMODEL;

    const int tid = threadIdx.x;
    const int lane = tid & 63, wave = tid >> 6;
    const int quad = lane >> 4, col = lane & 15;

    // XCD swizzle: lin = by*16+bx; xcd owns bx' = 2*xcd + (j&1), all by'
    const int lin = blockIdx.y * 16 + blockIdx.x;
    const int xcd = lin & 7, j8 = lin >> 3;          // j8 in [0,64)
    const int bxp = 2 * xcd + (j8 & 1);
    const int byp = j8 >> 1;
    const int m0 = byp * 128, n0 = bxp * 64;
    const int wm = wave >> 1, wn = wave & 1;

    const short* Asrc = Ab + (size_t)m0 * K;
    const short* Bhsrc = Bh + (size_t)n0 * K;
    const short* Blsrc = Bl + (size_t)n0 * K;
    const int srow = lane >> 3;
    const int soff = (((lane & 7) ^ srow) * 8);

    floatx4 acc[4][2] = {};

    OSTAGE(0, 0);
    for (int t = 0; t < 16; ++t) {
        const int db = t & 1;
        if (t < 15) {
            OSTAGE(db ^ 1, (t + 1) * 64);
            asm volatile("s_waitcnt vmcnt(8)" ::: "memory");
        } else {
            asm volatile("s_waitcnt vmcnt(0)" ::: "memory");
        }
        __builtin_amdgcn_s_barrier();

#pragma unroll
        for (int s2 = 0; s2 < 2; ++s2) {
            short8 a_b[4], b_h[2], b_l[2];
#pragma unroll
            for (int mi = 0; mi < 4; ++mi) {
                int r = wm * 64 + mi * 16 + col;
                a_b[mi] = *(const short8*)&sA[db][r * 64 + SWZ8(r, s2 * 4 + quad)];
            }
#pragma unroll
            for (int ni = 0; ni < 2; ++ni) {
                int r = wn * 32 + ni * 16 + col;
                b_h[ni] = *(const short8*)&sBh[db][r * 64 + SWZ8(r, s2 * 4 + quad)];
                b_l[ni] = *(const short8*)&sBl[db][r * 64 + SWZ8(r, s2 * 4 + quad)];
            }
            __builtin_amdgcn_s_setprio(1);
#pragma unroll
            for (int mi = 0; mi < 4; ++mi)
#pragma unroll
                for (int ni = 0; ni < 2; ++ni) {
                    acc[mi][ni] = MFMA16(b_h[ni], a_b[mi], acc[mi][ni], 0, 0, 0);
                    acc[mi][ni] = MFMA16(b_l[ni], a_b[mi], acc[mi][ni], 0, 0, 0);
                }
            __builtin_amdgcn_s_setprio(0);
        }
        __builtin_amdgcn_s_barrier();
    }

    const int mb = m0 + wm * 64, nb = n0 + wn * 32;
#pragma unroll
    for (int mi = 0; mi < 4; ++mi) {
        int m = mb + mi * 16 + col;
#pragma unroll
        for (int ni = 0; ni < 2; ++ni) {
            int n = nb + ni * 16 + quad * 4;
            float4 bv = *(const float4*)&bias[n];
            float4 o = make_float4(acc[mi][ni][0] + bv.x, acc[mi][ni][1] + bv.y,
                                   acc[mi][ni][2] + bv.z, acc[mi][ni][3] + bv.w);
            *(float4*)&Of[(size_t)m * N + n] = o;
        }
    }
}

// ---------------------------------------------------------------------------
extern "C" void kernel_launch(void* const* d_in, const int* in_sizes, int n_in,
                              void* d_out, int out_size, void* d_ws, size_t ws_size,
                              hipStream_t stream) {
    const float* x  = (const float*)d_in[0];
    const float* Wq = (const float*)d_in[1];
    const float* Wk = (const float*)d_in[2];
    const float* Wv = (const float*)d_in[3];
    const float* Wo = (const float*)d_in[4];
    const float* bo = (const float*)d_in[5];
    float* out = (float*)d_out;

    const size_t NX = (size_t)BROWS * DMODEL;   // 4M
    const size_t NW = (size_t)DMODEL * DMODEL;  // 1M
    short* p = (short*)d_ws;
    short *xb = p;
    short *wqb = xb + NX;
    short *wkb = wqb + NW;
    short *wvb = wkb + NW;
    short *woh = wvb + NW; short *wol = woh + NW;
    short *qb = wol + NW;
    short *kb = qb + NX;
    short *vb = kb + NX;
    short *cb = vb + NX;

    PackArgs pa;
    pa.x = (const float4*)x; pa.xb = (ushort4*)xb;
    pa.w[0] = (const float4*)Wq; pa.wb[0] = (ushort4*)wqb;
    pa.w[1] = (const float4*)Wk; pa.wb[1] = (ushort4*)wkb;
    pa.w[2] = (const float4*)Wv; pa.wb[2] = (ushort4*)wvb;
    pa.wo = (const float4*)Wo; pa.woh = (ushort4*)woh; pa.wol = (ushort4*)wol;
    pack_all<<<dim3(1024, 5), dim3(256), 0, stream>>>(pa);

    gemm_qkv<<<dim3(3 * DMODEL / 128, BROWS / 128), dim3(256), 0, stream>>>(
        xb, wqb, wkb, wvb, qb, kb, vb);

    attn_bf16<<<dim3(TSEQ / 128, BH), dim3(512), 0, stream>>>(qb, kb, vb, cb);

    gemm_out<<<dim3(DMODEL / 64, BROWS / 128), dim3(256), 0, stream>>>(cb, woh, wol, bo, out);
}

// Round 8
// 180.399 us; speedup vs baseline: 1.1229x; 1.0142x over previous
//
#include <hip/hip_runtime.h>
#include <hip/hip_bf16.h>
#include <math.h>
#include <stdint.h>
#include <string.h>

#define TSEQ 2048
#define DMODEL 1024
#define NH 16
#define HD 64
#define BROWS 4096   // b*t
#define BH 32        // b*h

typedef __attribute__((ext_vector_type(8))) short short8;
typedef __attribute__((ext_vector_type(4))) float floatx4;

#define MFMA16 __builtin_amdgcn_mfma_f32_16x16x32_bf16
// 3-bit chunk-XOR swizzle on 64-short (128 B) rows
#define SWZ8(r, q) ((((q) ^ ((r) & 7)) * 8))

#define QSCALE 0.18033688011112042f   // 0.125 * log2(e); p = exp2(s) = exp(s/log2e)

__device__ __forceinline__ unsigned short bf16_rne(float f) {
    uint32_t u = __float_as_uint(f);
    u += 0x7FFFu + ((u >> 16) & 1u);
    return (unsigned short)(u >> 16);
}

__device__ __forceinline__ uint32_t pack_bf16x2(float a, float b) {
    __hip_bfloat162 h = __float22bfloat162_rn(float2{a, b});
    uint32_t r;
    memcpy(&r, &h, 4);
    return r;
}

__device__ __forceinline__ void split_bf16(float f, short& hi, short& lo) {
    uint32_t u = __float_as_uint(f);
    hi = (short)(u >> 16);
    float hif = __uint_as_float(u & 0xFFFF0000u);
    lo = (short)bf16_rne(f - hif);
}

__device__ __forceinline__ void async16(const void* g, void* l) {
    __builtin_amdgcn_global_load_lds(
        (__attribute__((address_space(1))) const uint32_t*)g,
        (__attribute__((address_space(3))) uint32_t*)l, 16, 0, 0);
}

// ---------------------------------------------------------------------------
// Fused pack (unchanged)
// ---------------------------------------------------------------------------
struct PackArgs {
    const float4* x;
    ushort4* xb;
    const float4* w[3];   // Wq, Wk, Wv
    ushort4* wb[3];
    const float4* wo;
    ushort4* woh;
    ushort4* wol;
};
__global__ __launch_bounds__(256) void pack_all(PackArgs a) {
    const int y = blockIdx.y;
    const int base = blockIdx.x * 256 + threadIdx.x;
    if (y == 0) {
#pragma unroll
        for (int it = 0; it < 4; ++it) {
            int i = base + it * 262144;
            float4 f = a.x[i];
            a.xb[i] = make_ushort4(bf16_rne(f.x), bf16_rne(f.y),
                                   bf16_rne(f.z), bf16_rne(f.w));
        }
    } else if (y <= 3) {
        int w = y - 1;
        float4 f = a.w[w][base];
        a.wb[w][base] = make_ushort4(bf16_rne(f.x), bf16_rne(f.y),
                                     bf16_rne(f.z), bf16_rne(f.w));
    } else {
        float4 f = a.wo[base];
        short h0, l0, h1, l1, h2, l2, h3, l3;
        split_bf16(f.x, h0, l0); split_bf16(f.y, h1, l1);
        split_bf16(f.z, h2, l2); split_bf16(f.w, h3, l3);
        a.woh[base] = make_ushort4(h0, h1, h2, h3);
        a.wol[base] = make_ushort4(l0, l1, l2, l3);
    }
}

// ---------------------------------------------------------------------------
// Fused QKV GEMM, R8: 128x128, BK=64, now 512 thr / 8 WAVES (wave = 32x64,
// acc[2][4]) -> 2 blocks/CU x 8 waves = 4 waves/SIMD (2x R7) to fill MFMA
// issue while the co-resident block stalls on vmcnt. dbuf LDS 64 KB,
// counted vmcnt(4) (4 loads/wave/tile). XCD swizzle kept (FETCH-verified).
// ---------------------------------------------------------------------------
#define QSTAGE(DB, K0)                                                          \
    {                                                                           \
        _Pragma("unroll")                                                       \
        for (int j = 0; j < 4; ++j) {                                           \
            int idx = wave * 4 + j;                                             \
            int sub = idx & 15;                                                 \
            const short* s = (idx < 16) ? Asrc : Bsrc;                          \
            short* d = (idx < 16) ? sA[DB] : sB[DB];                            \
            async16(s + (size_t)(sub * 8 + srow) * K + (K0) + soff, d + sub * 512); \
        }                                                                       \
    }

__global__ __launch_bounds__(512, 4) void gemm_qkv(
    const short* __restrict__ Xb,
    const short* __restrict__ Bq, const short* __restrict__ Bk,
    const short* __restrict__ Bv,
    short* __restrict__ Qo, short* __restrict__ Ko, short* __restrict__ Vo) {
    __shared__ short sA[2][128 * 64];
    __shared__ short sB[2][128 * 64];
    const int K = DMODEL;

    const int tid = threadIdx.x;
    const int lane = tid & 63, wave = tid >> 6;
    const int quad = lane >> 4, col = lane & 15;

    // XCD swizzle: lin = by*24+bx; xcd owns bx' = 3*xcd + (j%3), all by'
    const int lin = blockIdx.y * 24 + blockIdx.x;
    const int xcd = lin & 7, j8 = lin >> 3;          // j8 in [0,96)
    const int bxp = 3 * xcd + (j8 % 3);
    const int byp = j8 / 3;
    const int m0 = byp * 128, n0 = bxp * 128;
    const int which = n0 >> 10;
    const int nn0 = n0 & 1023;
    const int wm = wave >> 1, wn = wave & 1;   // 4M x 2N -> 32x64 per wave

    const short* B = (which == 0) ? Bq : (which == 1) ? Bk : Bv;
    const short* Asrc = Xb + (size_t)m0 * K;
    const short* Bsrc = B + (size_t)nn0 * K;

    const int srow = lane >> 3;
    const int soff = (((lane & 7) ^ srow) * 8);

    floatx4 acc[2][4] = {};

    QSTAGE(0, 0);
    for (int t = 0; t < 16; ++t) {
        const int db = t & 1;
        if (t < 15) {
            QSTAGE(db ^ 1, (t + 1) * 64);
            asm volatile("s_waitcnt vmcnt(4)" ::: "memory");
        } else {
            asm volatile("s_waitcnt vmcnt(0)" ::: "memory");
        }
        __builtin_amdgcn_s_barrier();

#pragma unroll
        for (int s2 = 0; s2 < 2; ++s2) {
            short8 a_b[2], b_b[4];
#pragma unroll
            for (int mi = 0; mi < 2; ++mi) {
                int r = wm * 32 + mi * 16 + col;
                a_b[mi] = *(const short8*)&sA[db][r * 64 + SWZ8(r, s2 * 4 + quad)];
            }
#pragma unroll
            for (int ni = 0; ni < 4; ++ni) {
                int r = wn * 64 + ni * 16 + col;
                b_b[ni] = *(const short8*)&sB[db][r * 64 + SWZ8(r, s2 * 4 + quad)];
            }
            __builtin_amdgcn_s_setprio(1);
            if (which == 2) {
#pragma unroll
                for (int mi = 0; mi < 2; ++mi)
#pragma unroll
                    for (int ni = 0; ni < 4; ++ni)
                        acc[mi][ni] = MFMA16(a_b[mi], b_b[ni], acc[mi][ni], 0, 0, 0);
            } else {
#pragma unroll
                for (int mi = 0; mi < 2; ++mi)
#pragma unroll
                    for (int ni = 0; ni < 4; ++ni)
                        acc[mi][ni] = MFMA16(b_b[ni], a_b[mi], acc[mi][ni], 0, 0, 0);
            }
            __builtin_amdgcn_s_setprio(0);
        }
        __builtin_amdgcn_s_barrier();
    }

    const int mb = m0 + wm * 32;
    const int nlb = nn0 + wn * 64;
    if (which == 2) {
        // V^T [bh][hd][t], kappa-permuted window position + chunk-XOR swizzle
#pragma unroll
        for (int ni = 0; ni < 4; ++ni) {
            int n = nlb + ni * 16 + col;
            int h = n >> 6, hd = n & 63;
#pragma unroll
            for (int mi = 0; mi < 2; ++mi) {
                int m4 = mb + mi * 16 + quad * 4;
                int b = m4 >> 11, t0 = m4 & 2047;
                // kappa^-1: key bits [t5][t4][t3t2][t1t0] -> s = [t5][t3t2][t4][t1t0]
                int sw = (t0 & 32) | ((t0 & 12) << 1) | ((t0 & 16) >> 2);
                int tsw = (t0 & ~63) | ((((sw >> 3) ^ (hd & 7)) << 3) | (sw & 7));
                size_t row = ((size_t)(b * NH + h) * HD + hd) * TSEQ;
                *(ushort4*)&Vo[row + tsw] =
                    make_ushort4(bf16_rne(acc[mi][ni][0]), bf16_rne(acc[mi][ni][1]),
                                 bf16_rne(acc[mi][ni][2]), bf16_rne(acc[mi][ni][3]));
            }
        }
    } else {
        short* O = (which == 0) ? Qo : Ko;
        const float sc = (which == 0) ? QSCALE : 1.0f;
#pragma unroll
        for (int mi = 0; mi < 2; ++mi) {
            int m = mb + mi * 16 + col;
            int b = m >> 11, t = m & 2047;
#pragma unroll
            for (int ni = 0; ni < 4; ++ni) {
                int n = nlb + ni * 16 + quad * 4;
                int h = n >> 6, hd = n & 63;
                int hds = (which == 1) ? ((((hd >> 3) ^ (t & 7)) << 3) | (hd & 7)) : hd;
                size_t idx = ((size_t)(b * NH + h) * TSEQ + t) * HD + hds;
                *(ushort4*)&O[idx] =
                    make_ushort4(bf16_rne(acc[mi][ni][0] * sc), bf16_rne(acc[mi][ni][1] * sc),
                                 bf16_rne(acc[mi][ni][2] * sc), bf16_rne(acc[mi][ni][3] * sc));
            }
        }
    }
}

// ---------------------------------------------------------------------------
// Flash attention, R8: R3 structure + T15 2-deep software pipeline inside
// each 128-key tile: QK(u0) -> exp/pack(u0) -> QK(u1) -> {PV(u0) MFMA
// INTERLEAVED with exp/pack(u1) VALU} -> PV(u1). Register-only change; both
// u-subtiles live in the same dbuf -> no race. XCD swizzle reverted (R7
// showed FETCH -5.6x but dur +2us: attn is not BW-bound).
// ---------------------------------------------------------------------------
#define QK_U(DB, U, S)                                                          \
    {                                                                           \
        __builtin_amdgcn_s_setprio(1);                                          \
        _Pragma("unroll")                                                       \
        for (int k4 = 0; k4 < 4; ++k4) {                                        \
            short8 kf0 = *(const short8*)(kb0 + (DB) * 8192 + (U) * 4096 + k4 * 1024); \
            short8 kf1 = *(const short8*)(kb1 + (DB) * 8192 + (U) * 4096 + k4 * 1024); \
            S[k4] = MFMA16(kf0, qf[0], S[k4], 0, 0, 0);                         \
            S[k4] = MFMA16(kf1, qf[1], S[k4], 0, 0, 0);                         \
        }                                                                       \
        __builtin_amdgcn_s_setprio(0);                                          \
    }

// pf word c from s: 8 exp2 + 4 cvt_pk
#define EXPPACK_C(S, C, PFW)                                                    \
    {                                                                           \
        float p0 = __builtin_amdgcn_exp2f(S[2 * (C)][0]);                       \
        float p1 = __builtin_amdgcn_exp2f(S[2 * (C)][1]);                       \
        float p2 = __builtin_amdgcn_exp2f(S[2 * (C)][2]);                       \
        float p3 = __builtin_amdgcn_exp2f(S[2 * (C)][3]);                       \
        float p4 = __builtin_amdgcn_exp2f(S[2 * (C) + 1][0]);                   \
        float p5 = __builtin_amdgcn_exp2f(S[2 * (C) + 1][1]);                   \
        float p6 = __builtin_amdgcn_exp2f(S[2 * (C) + 1][2]);                   \
        float p7 = __builtin_amdgcn_exp2f(S[2 * (C) + 1][3]);                   \
        PFW.w[0] = pack_bf16x2(p0, p1);                                         \
        PFW.w[1] = pack_bf16x2(p2, p3);                                         \
        PFW.w[2] = pack_bf16x2(p4, p5);                                         \
        PFW.w[3] = pack_bf16x2(p6, p7);                                         \
    }

#define PV_C(DB, U, C, PFW)                                                     \
    {                                                                           \
        const short* vbc = (C) ? vb1 : vb0;                                     \
        __builtin_amdgcn_s_setprio(1);                                          \
        lacc = MFMA16(ones.v, PFW.v, lacc, 0, 0, 0);                            \
        _Pragma("unroll")                                                       \
        for (int ni = 0; ni < 4; ++ni) {                                        \
            short8 vf = *(const short8*)(vbc + (DB) * 8192 + (U) * 4096 + ni * 1024); \
            O[ni] = MFMA16(vf, PFW.v, O[ni], 0, 0, 0);                          \
        }                                                                       \
        __builtin_amdgcn_s_setprio(0);                                          \
    }

typedef union { short8 v; uint32_t w[4]; } pfu;

#define ATTN_COMPUTE(DB)                                                        \
    {                                                                           \
        floatx4 sa[4] = {};                                                     \
        QK_U(DB, 0, sa);                                                        \
        pfu pfA0, pfA1;                                                         \
        EXPPACK_C(sa, 0, pfA0);                                                 \
        EXPPACK_C(sa, 1, pfA1);                                                 \
        floatx4 sb[4] = {};                                                     \
        QK_U(DB, 1, sb);                                                        \
        /* PV(u0) MFMA interleaved with exp/pack(u1) VALU (independent) */      \
        pfu pfB0, pfB1;                                                         \
        PV_C(DB, 0, 0, pfA0);                                                   \
        EXPPACK_C(sb, 0, pfB0);                                                 \
        PV_C(DB, 0, 1, pfA1);                                                   \
        EXPPACK_C(sb, 1, pfB1);                                                 \
        PV_C(DB, 1, 0, pfB0);                                                   \
        PV_C(DB, 1, 1, pfB1);                                                   \
    }

#define ASTAGE(LB)                                                              \
    {                                                                           \
        async16(g0, (LB) + 0 * 512);                                            \
        async16(g1, (LB) + 1 * 512);                                            \
        async16(g2, (LB) + 2 * 512);                                            \
        async16(g3, (LB) + 3 * 512);                                            \
        g0 += ktstep; g1 += ktstep; g2 += ktstep; g3 += ktstep;                 \
    }

__global__ __launch_bounds__(512, 4) void attn_bf16(
    const short* __restrict__ Qb, const short* __restrict__ Kb,
    const short* __restrict__ Vb, short* __restrict__ Cb) {
    __shared__ short sK[2][2][64 * 64];   // [dbuf][tile]
    __shared__ short sV[2][2][64 * 64];

    const int tid = threadIdx.x;
    const int lane = tid & 63, wave = tid >> 6;
    const int quad = lane >> 4, col = lane & 15;
    const int qt = blockIdx.x, bh = blockIdx.y;
    const size_t bhoff = (size_t)bh * TSEQ * HD;

    // Q as B-operand frags: B[n=q=col][k=quad*8+j]
    const size_t qrow = (size_t)(qt * 128 + wave * 16 + col) * HD;
    short8 qf[2];
#pragma unroll
    for (int c = 0; c < 2; ++c)
        qf[c] = *(const short8*)&Qb[bhoff + qrow + c * 32 + quad * 8];

    const int srow = lane >> 3;
    const int schunk = (lane & 7) * 8;   // K/V globally pre-swizzled

    // staging geometry: wave w stages 4 slots n = w*4 + j
    const int isV = wave >> 2;
    const int tl = (wave >> 1) & 1;
    const int sb = (wave & 1) * 4;

    const short *g0, *g1, *g2, *g3;
    size_t ktstep;
    if (!isV) {
        g0 = Kb + bhoff + (size_t)(tl * 64 + (sb + 0) * 8 + srow) * HD + schunk;
        g1 = Kb + bhoff + (size_t)(tl * 64 + (sb + 1) * 8 + srow) * HD + schunk;
        g2 = Kb + bhoff + (size_t)(tl * 64 + (sb + 2) * 8 + srow) * HD + schunk;
        g3 = Kb + bhoff + (size_t)(tl * 64 + (sb + 3) * 8 + srow) * HD + schunk;
        ktstep = (size_t)128 * HD;
    } else {
        g0 = Vb + bhoff + (size_t)((sb + 0) * 8 + srow) * TSEQ + tl * 64 + schunk;
        g1 = Vb + bhoff + (size_t)((sb + 1) * 8 + srow) * TSEQ + tl * 64 + schunk;
        g2 = Vb + bhoff + (size_t)((sb + 2) * 8 + srow) * TSEQ + tl * 64 + schunk;
        g3 = Vb + bhoff + (size_t)((sb + 3) * 8 + srow) * TSEQ + tl * 64 + schunk;
        ktstep = 128;
    }
    short* lb0_ = isV ? &sV[0][tl][sb * 512] : &sK[0][tl][sb * 512];
    short* lb1_ = isV ? &sV[1][tl][sb * 512] : &sK[1][tl][sb * 512];

    // LDS fragment-read bases: all ds_reads are base + compile-time imm.
    const int ch0 = ((quad ^ (col & 7)) << 3);
    const int ch1 = (((4 + quad) ^ (col & 7)) << 3);
    const short* kb0 = &sK[0][0][col * 64 + ch0];
    const short* kb1 = &sK[0][0][col * 64 + ch1];
    const short* vb0 = &sV[0][0][col * 64 + ch0];
    const short* vb1 = &sV[0][0][col * 64 + ch1];

    // bf16 1.0 x8 for the l-accumulating MFMA
    union { short8 v; short s[8]; } ones;
#pragma unroll
    for (int j = 0; j < 8; ++j) ones.s[j] = (short)0x3F80;

    floatx4 lacc = {};      // every element = running l for q = col
    floatx4 O[4] = {};      // O^T: hd = ni*16 + quad*4 + r, q = col

    ASTAGE(lb0_);           // tile 0 -> db0

    for (int kt2 = 0; kt2 < 8; ++kt2) {
        ASTAGE(lb1_);
        asm volatile("s_waitcnt vmcnt(4)" ::: "memory");
        __builtin_amdgcn_s_barrier();
        ATTN_COMPUTE(0);
        __builtin_amdgcn_s_barrier();

        if (kt2 < 7) {
            ASTAGE(lb0_);
            asm volatile("s_waitcnt vmcnt(4)" ::: "memory");
        } else {
            asm volatile("s_waitcnt vmcnt(0)" ::: "memory");
        }
        __builtin_amdgcn_s_barrier();
        ATTN_COMPUTE(1);
        __builtin_amdgcn_s_barrier();
    }

    // l is fully summed over all keys by the ones-MFMA (B-layout spans k=0..31)
    const float inv = 1.0f / lacc[0];

    const int b = bh >> 4, h = bh & 15;
    const int trow = qt * 128 + wave * 16 + col;
    const size_t obase = (size_t)(b * TSEQ + trow) * DMODEL + h * 64;
#pragma unroll
    for (int ni = 0; ni < 4; ++ni) {
        uint2 pk;
        pk.x = pack_bf16x2(O[ni][0] * inv, O[ni][1] * inv);
        pk.y = pack_bf16x2(O[ni][2] * inv, O[ni][3] * inv);
        *(uint2*)&Cb[obase + ni * 16 + quad * 4] = pk;
    }
}

// ---------------------------------------------------------------------------
// Out-proj 2-term (R7 form: dbuf + vmcnt(8) + XCD swizzle). Unchanged.
// ---------------------------------------------------------------------------
#define OSTAGE(DB, K0)                                                          \
    {                                                                           \
        _Pragma("unroll")                                                       \
        for (int j = 0; j < 8; ++j) {                                           \
            int idx = wave * 8 + j;                                             \
            int buf = (idx < 16) ? 0 : (idx < 24) ? 1 : 2;                      \
            int sub = (buf == 0) ? idx : (buf == 1) ? idx - 16 : idx - 24;      \
            const short* s = (buf == 0) ? Asrc : (buf == 1) ? Bhsrc : Blsrc;    \
            short* d = (buf == 0) ? sA[DB] : (buf == 1) ? sBh[DB] : sBl[DB];    \
            async16(s + (size_t)(sub * 8 + srow) * K + (K0) + soff, d + sub * 512); \
        }                                                                       \
    }

__global__ __launch_bounds__(256) void gemm_out(
    const short* __restrict__ Ab,
    const short* __restrict__ Bh, const short* __restrict__ Bl,
    const float* __restrict__ bias, float* __restrict__ Of) {
    __shared__ short sA[2][128 * 64];
    __shared__ short sBh[2][64 * 64];
    __shared__ short sBl[2][64 * 64];
    const int K = DMODEL, N = DMODEL;

    const int tid = threadIdx.x;
    const int lane = tid & 63, wave = tid >> 6;
    const int quad = lane >> 4, col = lane & 15;

    // XCD swizzle: lin = by*16+bx; xcd owns bx' = 2*xcd + (j&1), all by'
    const int lin = blockIdx.y * 16 + blockIdx.x;
    const int xcd = lin & 7, j8 = lin >> 3;          // j8 in [0,64)
    const int bxp = 2 * xcd + (j8 & 1);
    const int byp = j8 >> 1;
    const int m0 = byp * 128, n0 = bxp * 64;
    const int wm = wave >> 1, wn = wave & 1;

    const short* Asrc = Ab + (size_t)m0 * K;
    const short* Bhsrc = Bh + (size_t)n0 * K;
    const short* Blsrc = Bl + (size_t)n0 * K;
    const int srow = lane >> 3;
    const int soff = (((lane & 7) ^ srow) * 8);

    floatx4 acc[4][2] = {};

    OSTAGE(0, 0);
    for (int t = 0; t < 16; ++t) {
        const int db = t & 1;
        if (t < 15) {
            OSTAGE(db ^ 1, (t + 1) * 64);
            asm volatile("s_waitcnt vmcnt(8)" ::: "memory");
        } else {
            asm volatile("s_waitcnt vmcnt(0)" ::: "memory");
        }
        __builtin_amdgcn_s_barrier();

#pragma unroll
        for (int s2 = 0; s2 < 2; ++s2) {
            short8 a_b[4], b_h[2], b_l[2];
#pragma unroll
            for (int mi = 0; mi < 4; ++mi) {
                int r = wm * 64 + mi * 16 + col;
                a_b[mi] = *(const short8*)&sA[db][r * 64 + SWZ8(r, s2 * 4 + quad)];
            }
#pragma unroll
            for (int ni = 0; ni < 2; ++ni) {
                int r = wn * 32 + ni * 16 + col;
                b_h[ni] = *(const short8*)&sBh[db][r * 64 + SWZ8(r, s2 * 4 + quad)];
                b_l[ni] = *(const short8*)&sBl[db][r * 64 + SWZ8(r, s2 * 4 + quad)];
            }
            __builtin_amdgcn_s_setprio(1);
#pragma unroll
            for (int mi = 0; mi < 4; ++mi)
#pragma unroll
                for (int ni = 0; ni < 2; ++ni) {
                    acc[mi][ni] = MFMA16(b_h[ni], a_b[mi], acc[mi][ni], 0, 0, 0);
                    acc[mi][ni] = MFMA16(b_l[ni], a_b[mi], acc[mi][ni], 0, 0, 0);
                }
            __builtin_amdgcn_s_setprio(0);
        }
        __builtin_amdgcn_s_barrier();
    }

    const int mb = m0 + wm * 64, nb = n0 + wn * 32;
#pragma unroll
    for (int mi = 0; mi < 4; ++mi) {
        int m = mb + mi * 16 + col;
#pragma unroll
        for (int ni = 0; ni < 2; ++ni) {
            int n = nb + ni * 16 + quad * 4;
            float4 bv = *(const float4*)&bias[n];
            float4 o = make_float4(acc[mi][ni][0] + bv.x, acc[mi][ni][1] + bv.y,
                                   acc[mi][ni][2] + bv.z, acc[mi][ni][3] + bv.w);
            *(float4*)&Of[(size_t)m * N + n] = o;
        }
    }
}

// ---------------------------------------------------------------------------
extern "C" void kernel_launch(void* const* d_in, const int* in_sizes, int n_in,
                              void* d_out, int out_size, void* d_ws, size_t ws_size,
                              hipStream_t stream) {
    const float* x  = (const float*)d_in[0];
    const float* Wq = (const float*)d_in[1];
    const float* Wk = (const float*)d_in[2];
    const float* Wv = (const float*)d_in[3];
    const float* Wo = (const float*)d_in[4];
    const float* bo = (const float*)d_in[5];
    float* out = (float*)d_out;

    const size_t NX = (size_t)BROWS * DMODEL;   // 4M
    const size_t NW = (size_t)DMODEL * DMODEL;  // 1M
    short* p = (short*)d_ws;
    short *xb = p;
    short *wqb = xb + NX;
    short *wkb = wqb + NW;
    short *wvb = wkb + NW;
    short *woh = wvb + NW; short *wol = woh + NW;
    short *qb = wol + NW;
    short *kb = qb + NX;
    short *vb = kb + NX;
    short *cb = vb + NX;

    PackArgs pa;
    pa.x = (const float4*)x; pa.xb = (ushort4*)xb;
    pa.w[0] = (const float4*)Wq; pa.wb[0] = (ushort4*)wqb;
    pa.w[1] = (const float4*)Wk; pa.wb[1] = (ushort4*)wkb;
    pa.w[2] = (const float4*)Wv; pa.wb[2] = (ushort4*)wvb;
    pa.wo = (const float4*)Wo; pa.woh = (ushort4*)woh; pa.wol = (ushort4*)wol;
    pack_all<<<dim3(1024, 5), dim3(256), 0, stream>>>(pa);

    gemm_qkv<<<dim3(3 * DMODEL / 128, BROWS / 128), dim3(512), 0, stream>>>(
        xb, wqb, wkb, wvb, qb, kb, vb);

    attn_bf16<<<dim3(TSEQ / 128, BH), dim3(512), 0, stream>>>(qb, kb, vb, cb);

    gemm_out<<<dim3(DMODEL / 64, BROWS / 128), dim3(256), 0, stream>>>(cb, woh, wol, bo, out);
}

// Round 9
// 178.554 us; speedup vs baseline: 1.1345x; 1.0103x over previous
//
#include <hip/hip_runtime.h>
#include <hip/hip_bf16.h>
#include <math.h>
#include <stdint.h>
#include <string.h>

#define TSEQ 2048
#define DMODEL 1024
#define NH 16
#define HD 64
#define BROWS 4096   // b*t
#define BH 32        // b*h

typedef __attribute__((ext_vector_type(8))) short short8;
typedef __attribute__((ext_vector_type(4))) float floatx4;

#define MFMA16 __builtin_amdgcn_mfma_f32_16x16x32_bf16
// 3-bit chunk-XOR swizzle on 64-short (128 B) rows
#define SWZ8(r, q) ((((q) ^ ((r) & 7)) * 8))

#define QSCALE 0.18033688011112042f   // 0.125 * log2(e); p = exp2(s) = exp(s/log2e)

__device__ __forceinline__ unsigned short bf16_rne(float f) {
    uint32_t u = __float_as_uint(f);
    u += 0x7FFFu + ((u >> 16) & 1u);
    return (unsigned short)(u >> 16);
}

__device__ __forceinline__ uint32_t pack_bf16x2(float a, float b) {
    __hip_bfloat162 h = __float22bfloat162_rn(float2{a, b});
    uint32_t r;
    memcpy(&r, &h, 4);
    return r;
}

__device__ __forceinline__ void split_bf16(float f, short& hi, short& lo) {
    uint32_t u = __float_as_uint(f);
    hi = (short)(u >> 16);
    float hif = __uint_as_float(u & 0xFFFF0000u);
    lo = (short)bf16_rne(f - hif);
}

__device__ __forceinline__ void async16(const void* g, void* l) {
    __builtin_amdgcn_global_load_lds(
        (__attribute__((address_space(1))) const uint32_t*)g,
        (__attribute__((address_space(3))) uint32_t*)l, 16, 0, 0);
}

// ---------------------------------------------------------------------------
// Fused pack (unchanged)
// ---------------------------------------------------------------------------
struct PackArgs {
    const float4* x;
    ushort4* xb;
    const float4* w[3];   // Wq, Wk, Wv
    ushort4* wb[3];
    const float4* wo;
    ushort4* woh;
    ushort4* wol;
};
__global__ __launch_bounds__(256) void pack_all(PackArgs a) {
    const int y = blockIdx.y;
    const int base = blockIdx.x * 256 + threadIdx.x;
    if (y == 0) {
#pragma unroll
        for (int it = 0; it < 4; ++it) {
            int i = base + it * 262144;
            float4 f = a.x[i];
            a.xb[i] = make_ushort4(bf16_rne(f.x), bf16_rne(f.y),
                                   bf16_rne(f.z), bf16_rne(f.w));
        }
    } else if (y <= 3) {
        int w = y - 1;
        float4 f = a.w[w][base];
        a.wb[w][base] = make_ushort4(bf16_rne(f.x), bf16_rne(f.y),
                                     bf16_rne(f.z), bf16_rne(f.w));
    } else {
        float4 f = a.wo[base];
        short h0, l0, h1, l1, h2, l2, h3, l3;
        split_bf16(f.x, h0, l0); split_bf16(f.y, h1, l1);
        split_bf16(f.z, h2, l2); split_bf16(f.w, h3, l3);
        a.woh[base] = make_ushort4(h0, h1, h2, h3);
        a.wol[base] = make_ushort4(l0, l1, l2, l3);
    }
}

// ---------------------------------------------------------------------------
// Fused QKV GEMM, R9 = R7 form (4 waves, 64x64/wave: best LDS-read ratio
// 0.5 reads/MFMA). 128x128, BK=64, dbuf 64 KB, counted vmcnt(8), XCD swizzle.
// ---------------------------------------------------------------------------
#define QSTAGE(DB, K0)                                                          \
    {                                                                           \
        _Pragma("unroll")                                                       \
        for (int j = 0; j < 8; ++j) {                                           \
            int idx = wave * 8 + j;                                             \
            int sub = idx & 15;                                                 \
            const short* s = (idx < 16) ? Asrc : Bsrc;                          \
            short* d = (idx < 16) ? sA[DB] : sB[DB];                            \
            async16(s + (size_t)(sub * 8 + srow) * K + (K0) + soff, d + sub * 512); \
        }                                                                       \
    }

__global__ __launch_bounds__(256) void gemm_qkv(
    const short* __restrict__ Xb,
    const short* __restrict__ Bq, const short* __restrict__ Bk,
    const short* __restrict__ Bv,
    short* __restrict__ Qo, short* __restrict__ Ko, short* __restrict__ Vo) {
    __shared__ short sA[2][128 * 64];
    __shared__ short sB[2][128 * 64];
    const int K = DMODEL;

    const int tid = threadIdx.x;
    const int lane = tid & 63, wave = tid >> 6;
    const int quad = lane >> 4, col = lane & 15;

    // XCD swizzle: lin = by*24+bx; xcd owns bx' = 3*xcd + (j%3), all by'
    const int lin = blockIdx.y * 24 + blockIdx.x;
    const int xcd = lin & 7, j8 = lin >> 3;          // j8 in [0,96)
    const int bxp = 3 * xcd + (j8 % 3);
    const int byp = j8 / 3;
    const int m0 = byp * 128, n0 = bxp * 128;
    const int which = n0 >> 10;
    const int nn0 = n0 & 1023;
    const int wm = wave >> 1, wn = wave & 1;

    const short* B = (which == 0) ? Bq : (which == 1) ? Bk : Bv;
    const short* Asrc = Xb + (size_t)m0 * K;
    const short* Bsrc = B + (size_t)nn0 * K;

    const int srow = lane >> 3;
    const int soff = (((lane & 7) ^ srow) * 8);

    floatx4 acc[4][4] = {};

    QSTAGE(0, 0);
    for (int t = 0; t < 16; ++t) {
        const int db = t & 1;
        if (t < 15) {
            QSTAGE(db ^ 1, (t + 1) * 64);
            asm volatile("s_waitcnt vmcnt(8)" ::: "memory");
        } else {
            asm volatile("s_waitcnt vmcnt(0)" ::: "memory");
        }
        __builtin_amdgcn_s_barrier();

#pragma unroll
        for (int s2 = 0; s2 < 2; ++s2) {
            short8 a_b[4], b_b[4];
#pragma unroll
            for (int mi = 0; mi < 4; ++mi) {
                int r = wm * 64 + mi * 16 + col;
                a_b[mi] = *(const short8*)&sA[db][r * 64 + SWZ8(r, s2 * 4 + quad)];
            }
#pragma unroll
            for (int ni = 0; ni < 4; ++ni) {
                int r = wn * 64 + ni * 16 + col;
                b_b[ni] = *(const short8*)&sB[db][r * 64 + SWZ8(r, s2 * 4 + quad)];
            }
            __builtin_amdgcn_s_setprio(1);
            if (which == 2) {
#pragma unroll
                for (int mi = 0; mi < 4; ++mi)
#pragma unroll
                    for (int ni = 0; ni < 4; ++ni)
                        acc[mi][ni] = MFMA16(a_b[mi], b_b[ni], acc[mi][ni], 0, 0, 0);
            } else {
#pragma unroll
                for (int mi = 0; mi < 4; ++mi)
#pragma unroll
                    for (int ni = 0; ni < 4; ++ni)
                        acc[mi][ni] = MFMA16(b_b[ni], a_b[mi], acc[mi][ni], 0, 0, 0);
            }
            __builtin_amdgcn_s_setprio(0);
        }
        __builtin_amdgcn_s_barrier();
    }

    const int mb = m0 + wm * 64;
    const int nlb = nn0 + wn * 64;
    if (which == 2) {
        // V^T [bh][hd][t], kappa-permuted window position + chunk-XOR swizzle
#pragma unroll
        for (int ni = 0; ni < 4; ++ni) {
            int n = nlb + ni * 16 + col;
            int h = n >> 6, hd = n & 63;
#pragma unroll
            for (int mi = 0; mi < 4; ++mi) {
                int m4 = mb + mi * 16 + quad * 4;
                int b = m4 >> 11, t0 = m4 & 2047;
                // kappa^-1: key bits [t5][t4][t3t2][t1t0] -> s = [t5][t3t2][t4][t1t0]
                int sw = (t0 & 32) | ((t0 & 12) << 1) | ((t0 & 16) >> 2);
                int tsw = (t0 & ~63) | ((((sw >> 3) ^ (hd & 7)) << 3) | (sw & 7));
                size_t row = ((size_t)(b * NH + h) * HD + hd) * TSEQ;
                *(ushort4*)&Vo[row + tsw] =
                    make_ushort4(bf16_rne(acc[mi][ni][0]), bf16_rne(acc[mi][ni][1]),
                                 bf16_rne(acc[mi][ni][2]), bf16_rne(acc[mi][ni][3]));
            }
        }
    } else {
        short* O = (which == 0) ? Qo : Ko;
        const float sc = (which == 0) ? QSCALE : 1.0f;
#pragma unroll
        for (int mi = 0; mi < 4; ++mi) {
            int m = mb + mi * 16 + col;
            int b = m >> 11, t = m & 2047;
#pragma unroll
            for (int ni = 0; ni < 4; ++ni) {
                int n = nlb + ni * 16 + quad * 4;
                int h = n >> 6, hd = n & 63;
                int hds = (which == 1) ? ((((hd >> 3) ^ (t & 7)) << 3) | (hd & 7)) : hd;
                size_t idx = ((size_t)(b * NH + h) * TSEQ + t) * HD + hds;
                *(ushort4*)&O[idx] =
                    make_ushort4(bf16_rne(acc[mi][ni][0] * sc), bf16_rne(acc[mi][ni][1] * sc),
                                 bf16_rne(acc[mi][ni][2] * sc), bf16_rne(acc[mi][ni][3] * sc));
            }
        }
    }
}

// ---------------------------------------------------------------------------
// Flash attention, R9: 4 waves x 32 q-rows (two q-groups A/B per wave).
// Each K/V LDS fragment is read ONCE and feeds MFMA for BOTH groups ->
// LDS reads per MFMA halve (R8 was LDS-throughput-bound: 6144 cyc LDS vs
// 2794 MFMA per CU per tile; now ~3072 vs ~2794, balanced).
// T15 interleave retained: PV(u0) MFMA overlaps exp/pack(u1) VALU.
// 256 thr, launch_bounds(256,2): <=256 VGPR, 2 blocks/CU (LDS-limited).
// ---------------------------------------------------------------------------
#define QK2_U(DB, U, SA, SB)                                                    \
    {                                                                           \
        __builtin_amdgcn_s_setprio(1);                                          \
        _Pragma("unroll")                                                       \
        for (int k4 = 0; k4 < 4; ++k4) {                                        \
            short8 kf0 = *(const short8*)(kb0 + (DB) * 8192 + (U) * 4096 + k4 * 1024); \
            short8 kf1 = *(const short8*)(kb1 + (DB) * 8192 + (U) * 4096 + k4 * 1024); \
            SA[k4] = MFMA16(kf0, qfA[0], SA[k4], 0, 0, 0);                      \
            SA[k4] = MFMA16(kf1, qfA[1], SA[k4], 0, 0, 0);                      \
            SB[k4] = MFMA16(kf0, qfB[0], SB[k4], 0, 0, 0);                      \
            SB[k4] = MFMA16(kf1, qfB[1], SB[k4], 0, 0, 0);                      \
        }                                                                       \
        __builtin_amdgcn_s_setprio(0);                                          \
    }

// pf word c from s: 8 exp2 + 4 cvt_pk
#define EXPPACK_C(S, C, PFW)                                                    \
    {                                                                           \
        float p0 = __builtin_amdgcn_exp2f(S[2 * (C)][0]);                       \
        float p1 = __builtin_amdgcn_exp2f(S[2 * (C)][1]);                       \
        float p2 = __builtin_amdgcn_exp2f(S[2 * (C)][2]);                       \
        float p3 = __builtin_amdgcn_exp2f(S[2 * (C)][3]);                       \
        float p4 = __builtin_amdgcn_exp2f(S[2 * (C) + 1][0]);                   \
        float p5 = __builtin_amdgcn_exp2f(S[2 * (C) + 1][1]);                   \
        float p6 = __builtin_amdgcn_exp2f(S[2 * (C) + 1][2]);                   \
        float p7 = __builtin_amdgcn_exp2f(S[2 * (C) + 1][3]);                   \
        PFW.w[0] = pack_bf16x2(p0, p1);                                         \
        PFW.w[1] = pack_bf16x2(p2, p3);                                         \
        PFW.w[2] = pack_bf16x2(p4, p5);                                         \
        PFW.w[3] = pack_bf16x2(p6, p7);                                         \
    }

// PV for both groups off one V-fragment read
#define PV2_C(DB, U, C, FA, FB)                                                 \
    {                                                                           \
        const short* vbc = (C) ? vb1 : vb0;                                     \
        __builtin_amdgcn_s_setprio(1);                                          \
        laccA = MFMA16(ones.v, FA.v, laccA, 0, 0, 0);                           \
        laccB = MFMA16(ones.v, FB.v, laccB, 0, 0, 0);                           \
        _Pragma("unroll")                                                       \
        for (int ni = 0; ni < 4; ++ni) {                                        \
            short8 vf = *(const short8*)(vbc + (DB) * 8192 + (U) * 4096 + ni * 1024); \
            OA[ni] = MFMA16(vf, FA.v, OA[ni], 0, 0, 0);                         \
            OB[ni] = MFMA16(vf, FB.v, OB[ni], 0, 0, 0);                         \
        }                                                                       \
        __builtin_amdgcn_s_setprio(0);                                          \
    }

typedef union { short8 v; uint32_t w[4]; } pfu;

#define ATTN_COMPUTE(DB)                                                        \
    {                                                                           \
        floatx4 saA[4] = {}, saB[4] = {};                                       \
        QK2_U(DB, 0, saA, saB);                                                 \
        pfu fA0, fA1, fB0, fB1;                                                 \
        EXPPACK_C(saA, 0, fA0);                                                 \
        EXPPACK_C(saA, 1, fA1);                                                 \
        EXPPACK_C(saB, 0, fB0);                                                 \
        EXPPACK_C(saB, 1, fB1);                                                 \
        floatx4 sbA[4] = {}, sbB[4] = {};                                       \
        QK2_U(DB, 1, sbA, sbB);                                                 \
        /* PV(u0) MFMA interleaved with exp/pack(u1) VALU (independent) */      \
        pfu gA0, gA1, gB0, gB1;                                                 \
        PV2_C(DB, 0, 0, fA0, fB0);                                              \
        EXPPACK_C(sbA, 0, gA0);                                                 \
        EXPPACK_C(sbB, 0, gB0);                                                 \
        PV2_C(DB, 0, 1, fA1, fB1);                                              \
        EXPPACK_C(sbA, 1, gA1);                                                 \
        EXPPACK_C(sbB, 1, gB1);                                                 \
        PV2_C(DB, 1, 0, gA0, gB0);                                              \
        PV2_C(DB, 1, 1, gA1, gB1);                                              \
    }

#define ASTAGE(LB)                                                              \
    {                                                                           \
        _Pragma("unroll")                                                       \
        for (int j = 0; j < 8; ++j)                                             \
            async16(gb + (size_t)j * gj, (LB) + j * 512);                       \
        gb += ktstep;                                                           \
    }

__global__ __launch_bounds__(256, 2) void attn_bf16(
    const short* __restrict__ Qb, const short* __restrict__ Kb,
    const short* __restrict__ Vb, short* __restrict__ Cb) {
    __shared__ short sK[2][2][64 * 64];   // [dbuf][tile]
    __shared__ short sV[2][2][64 * 64];

    const int tid = threadIdx.x;
    const int lane = tid & 63, wave = tid >> 6;   // wave 0..3
    const int quad = lane >> 4, col = lane & 15;
    const int qt = blockIdx.x, bh = blockIdx.y;
    const size_t bhoff = (size_t)bh * TSEQ * HD;

    // Two q-groups per wave: rows qt*128 + wave*32 + col (A) and +16 (B)
    const size_t qrowA = (size_t)(qt * 128 + wave * 32 + col) * HD;
    const size_t qrowB = qrowA + (size_t)16 * HD;
    short8 qfA[2], qfB[2];
#pragma unroll
    for (int c = 0; c < 2; ++c) {
        qfA[c] = *(const short8*)&Qb[bhoff + qrowA + c * 32 + quad * 8];
        qfB[c] = *(const short8*)&Qb[bhoff + qrowB + c * 32 + quad * 8];
    }

    const int srow = lane >> 3;
    const int schunk = (lane & 7) * 8;   // K/V globally pre-swizzled

    // staging: waves 0,1 = K tiles 0,1; waves 2,3 = V tiles 0,1; 8 loads/wave
    const int isV = wave >> 1, tl = wave & 1;
    const short* gb;
    size_t gj, ktstep;
    if (!isV) {
        gb = Kb + bhoff + (size_t)(tl * 64 + srow) * HD + schunk;
        gj = (size_t)8 * HD;
        ktstep = (size_t)128 * HD;
    } else {
        gb = Vb + bhoff + (size_t)srow * TSEQ + tl * 64 + schunk;
        gj = (size_t)8 * TSEQ;
        ktstep = 128;
    }
    short* lb0_ = isV ? sV[0][tl] : sK[0][tl];
    short* lb1_ = isV ? sV[1][tl] : sK[1][tl];

    // LDS fragment-read bases: all ds_reads are base + compile-time imm.
    const int ch0 = ((quad ^ (col & 7)) << 3);
    const int ch1 = (((4 + quad) ^ (col & 7)) << 3);
    const short* kb0 = &sK[0][0][col * 64 + ch0];
    const short* kb1 = &sK[0][0][col * 64 + ch1];
    const short* vb0 = &sV[0][0][col * 64 + ch0];
    const short* vb1 = &sV[0][0][col * 64 + ch1];

    // bf16 1.0 x8 for the l-accumulating MFMA
    union { short8 v; short s[8]; } ones;
#pragma unroll
    for (int j = 0; j < 8; ++j) ones.s[j] = (short)0x3F80;

    floatx4 laccA = {}, laccB = {};
    floatx4 OA[4] = {}, OB[4] = {};   // O^T per group

    ASTAGE(lb0_);           // tile 0 -> db0

    for (int kt2 = 0; kt2 < 8; ++kt2) {
        ASTAGE(lb1_);
        asm volatile("s_waitcnt vmcnt(8)" ::: "memory");
        __builtin_amdgcn_s_barrier();
        ATTN_COMPUTE(0);
        __builtin_amdgcn_s_barrier();

        if (kt2 < 7) {
            ASTAGE(lb0_);
            asm volatile("s_waitcnt vmcnt(8)" ::: "memory");
        } else {
            asm volatile("s_waitcnt vmcnt(0)" ::: "memory");
        }
        __builtin_amdgcn_s_barrier();
        ATTN_COMPUTE(1);
        __builtin_amdgcn_s_barrier();
    }

    const float invA = 1.0f / laccA[0];
    const float invB = 1.0f / laccB[0];

    const int b = bh >> 4, h = bh & 15;
    const int trowA = qt * 128 + wave * 32 + col;
    const size_t obaseA = (size_t)(b * TSEQ + trowA) * DMODEL + h * 64;
    const size_t obaseB = obaseA + (size_t)16 * DMODEL;
#pragma unroll
    for (int ni = 0; ni < 4; ++ni) {
        uint2 pk;
        pk.x = pack_bf16x2(OA[ni][0] * invA, OA[ni][1] * invA);
        pk.y = pack_bf16x2(OA[ni][2] * invA, OA[ni][3] * invA);
        *(uint2*)&Cb[obaseA + ni * 16 + quad * 4] = pk;
        uint2 pk2;
        pk2.x = pack_bf16x2(OB[ni][0] * invB, OB[ni][1] * invB);
        pk2.y = pack_bf16x2(OB[ni][2] * invB, OB[ni][3] * invB);
        *(uint2*)&Cb[obaseB + ni * 16 + quad * 4] = pk2;
    }
}

// ---------------------------------------------------------------------------
// Out-proj 2-term (R7 form: dbuf + vmcnt(8) + XCD swizzle). Unchanged.
// ---------------------------------------------------------------------------
#define OSTAGE(DB, K0)                                                          \
    {                                                                           \
        _Pragma("unroll")                                                       \
        for (int j = 0; j < 8; ++j) {                                           \
            int idx = wave * 8 + j;                                             \
            int buf = (idx < 16) ? 0 : (idx < 24) ? 1 : 2;                      \
            int sub = (buf == 0) ? idx : (buf == 1) ? idx - 16 : idx - 24;      \
            const short* s = (buf == 0) ? Asrc : (buf == 1) ? Bhsrc : Blsrc;    \
            short* d = (buf == 0) ? sA[DB] : (buf == 1) ? sBh[DB] : sBl[DB];    \
            async16(s + (size_t)(sub * 8 + srow) * K + (K0) + soff, d + sub * 512); \
        }                                                                       \
    }

__global__ __launch_bounds__(256) void gemm_out(
    const short* __restrict__ Ab,
    const short* __restrict__ Bh, const short* __restrict__ Bl,
    const float* __restrict__ bias, float* __restrict__ Of) {
    __shared__ short sA[2][128 * 64];
    __shared__ short sBh[2][64 * 64];
    __shared__ short sBl[2][64 * 64];
    const int K = DMODEL, N = DMODEL;

    const int tid = threadIdx.x;
    const int lane = tid & 63, wave = tid >> 6;
    const int quad = lane >> 4, col = lane & 15;

    // XCD swizzle: lin = by*16+bx; xcd owns bx' = 2*xcd + (j&1), all by'
    const int lin = blockIdx.y * 16 + blockIdx.x;
    const int xcd = lin & 7, j8 = lin >> 3;          // j8 in [0,64)
    const int bxp = 2 * xcd + (j8 & 1);
    const int byp = j8 >> 1;
    const int m0 = byp * 128, n0 = bxp * 64;
    const int wm = wave >> 1, wn = wave & 1;

    const short* Asrc = Ab + (size_t)m0 * K;
    const short* Bhsrc = Bh + (size_t)n0 * K;
    const short* Blsrc = Bl + (size_t)n0 * K;
    const int srow = lane >> 3;
    const int soff = (((lane & 7) ^ srow) * 8);

    floatx4 acc[4][2] = {};

    OSTAGE(0, 0);
    for (int t = 0; t < 16; ++t) {
        const int db = t & 1;
        if (t < 15) {
            OSTAGE(db ^ 1, (t + 1) * 64);
            asm volatile("s_waitcnt vmcnt(8)" ::: "memory");
        } else {
            asm volatile("s_waitcnt vmcnt(0)" ::: "memory");
        }
        __builtin_amdgcn_s_barrier();

#pragma unroll
        for (int s2 = 0; s2 < 2; ++s2) {
            short8 a_b[4], b_h[2], b_l[2];
#pragma unroll
            for (int mi = 0; mi < 4; ++mi) {
                int r = wm * 64 + mi * 16 + col;
                a_b[mi] = *(const short8*)&sA[db][r * 64 + SWZ8(r, s2 * 4 + quad)];
            }
#pragma unroll
            for (int ni = 0; ni < 2; ++ni) {
                int r = wn * 32 + ni * 16 + col;
                b_h[ni] = *(const short8*)&sBh[db][r * 64 + SWZ8(r, s2 * 4 + quad)];
                b_l[ni] = *(const short8*)&sBl[db][r * 64 + SWZ8(r, s2 * 4 + quad)];
            }
            __builtin_amdgcn_s_setprio(1);
#pragma unroll
            for (int mi = 0; mi < 4; ++mi)
#pragma unroll
                for (int ni = 0; ni < 2; ++ni) {
                    acc[mi][ni] = MFMA16(b_h[ni], a_b[mi], acc[mi][ni], 0, 0, 0);
                    acc[mi][ni] = MFMA16(b_l[ni], a_b[mi], acc[mi][ni], 0, 0, 0);
                }
            __builtin_amdgcn_s_setprio(0);
        }
        __builtin_amdgcn_s_barrier();
    }

    const int mb = m0 + wm * 64, nb = n0 + wn * 32;
#pragma unroll
    for (int mi = 0; mi < 4; ++mi) {
        int m = mb + mi * 16 + col;
#pragma unroll
        for (int ni = 0; ni < 2; ++ni) {
            int n = nb + ni * 16 + quad * 4;
            float4 bv = *(const float4*)&bias[n];
            float4 o = make_float4(acc[mi][ni][0] + bv.x, acc[mi][ni][1] + bv.y,
                                   acc[mi][ni][2] + bv.z, acc[mi][ni][3] + bv.w);
            *(float4*)&Of[(size_t)m * N + n] = o;
        }
    }
}

// ---------------------------------------------------------------------------
extern "C" void kernel_launch(void* const* d_in, const int* in_sizes, int n_in,
                              void* d_out, int out_size, void* d_ws, size_t ws_size,
                              hipStream_t stream) {
    const float* x  = (const float*)d_in[0];
    const float* Wq = (const float*)d_in[1];
    const float* Wk = (const float*)d_in[2];
    const float* Wv = (const float*)d_in[3];
    const float* Wo = (const float*)d_in[4];
    const float* bo = (const float*)d_in[5];
    float* out = (float*)d_out;

    const size_t NX = (size_t)BROWS * DMODEL;   // 4M
    const size_t NW = (size_t)DMODEL * DMODEL;  // 1M
    short* p = (short*)d_ws;
    short *xb = p;
    short *wqb = xb + NX;
    short *wkb = wqb + NW;
    short *wvb = wkb + NW;
    short *woh = wvb + NW; short *wol = woh + NW;
    short *qb = wol + NW;
    short *kb = qb + NX;
    short *vb = kb + NX;
    short *cb = vb + NX;

    PackArgs pa;
    pa.x = (const float4*)x; pa.xb = (ushort4*)xb;
    pa.w[0] = (const float4*)Wq; pa.wb[0] = (ushort4*)wqb;
    pa.w[1] = (const float4*)Wk; pa.wb[1] = (ushort4*)wkb;
    pa.w[2] = (const float4*)Wv; pa.wb[2] = (ushort4*)wvb;
    pa.wo = (const float4*)Wo; pa.woh = (ushort4*)woh; pa.wol = (ushort4*)wol;
    pack_all<<<dim3(1024, 5), dim3(256), 0, stream>>>(pa);

    gemm_qkv<<<dim3(3 * DMODEL / 128, BROWS / 128), dim3(256), 0, stream>>>(
        xb, wqb, wkb, wvb, qb, kb, vb);

    attn_bf16<<<dim3(TSEQ / 128, BH), dim3(256), 0, stream>>>(qb, kb, vb, cb);

    gemm_out<<<dim3(DMODEL / 64, BROWS / 128), dim3(256), 0, stream>>>(cb, woh, wol, bo, out);
}